// Round 1
// 208.643 us; speedup vs baseline: 1.0106x; 1.0106x over previous
//
#include <hip/hip_runtime.h>
#include <hip/hip_bf16.h>

// ---- problem constants ----
#define BB 2
#define SS 2048
#define DMODEL 1024
#define NHEADS 16
#define DHEAD 64
#define MTOT (BB*SS)      // 4096
#define NQKV 3072
#define QSCALE 0.18033688011112042f   // 0.125 * log2(e), folded into Q at projection

typedef short bh8 __attribute__((ext_vector_type(8)));   // 8 bf16 (4 VGPRs)
typedef float fx4 __attribute__((ext_vector_type(4)));   // MFMA accumulator
typedef unsigned int ux2 __attribute__((ext_vector_type(2)));

__device__ __forceinline__ short f2bs(float f) {
    __hip_bfloat16 h = __float2bfloat16(f);
    return *reinterpret_cast<short*>(&h);
}

__device__ __forceinline__ unsigned pk_bf16(float a, float b) {
    __hip_bfloat162 h = __float22bfloat162_rn(make_float2(a, b));
    return *reinterpret_cast<unsigned*>(&h);
}

// async global->LDS, 16B per lane. LDS dest wave-uniform base + lane*16.
__device__ __forceinline__ void gload_lds16(const short* g, short* l) {
    __builtin_amdgcn_global_load_lds(
        (const __attribute__((address_space(1))) unsigned int*)g,
        (__attribute__((address_space(3))) unsigned int*)l, 16, 0, 0);
}

// ---------------- prep: fp32 -> bf16 elementwise ----------------
__global__ __launch_bounds__(256) void cvt_emb(const float* __restrict__ x,
                                               short* __restrict__ y, int n) {
    int i = (blockIdx.x * 256 + threadIdx.x) * 4;
    if (i + 3 < n) {
        float4 v = *(const float4*)(x + i);
        short4 o;
        o.x = f2bs(v.x); o.y = f2bs(v.y); o.z = f2bs(v.z); o.w = f2bs(v.w);
        *(short4*)(y + i) = o;
    }
}

// ------------- prep: transpose + convert weights (1024x1024 each) -------------
__global__ __launch_bounds__(256) void transpose_w(
        const float* __restrict__ Wq, const float* __restrict__ Wk,
        const float* __restrict__ Wv, const float* __restrict__ Wo,
        short* __restrict__ Wt_qkv, short* __restrict__ Wot) {
    __shared__ float tile[64][65];
    int z = blockIdx.z;
    const float* src = (z == 0) ? Wq : (z == 1) ? Wk : (z == 2) ? Wv : Wo;
    short* dst = (z == 3) ? Wot : (Wt_qkv + (size_t)z * 1024 * 1024);
    int n0 = blockIdx.x * 64, k0 = blockIdx.y * 64;
    int tx = threadIdx.x, ty = threadIdx.y;
    for (int j = 0; j < 16; j++) {
        int r = ty + j * 4;
        tile[r][tx] = src[(size_t)(k0 + r) * 1024 + n0 + tx];
    }
    __syncthreads();
    for (int j = 0; j < 16; j++) {
        int r = ty + j * 4;
        dst[(size_t)(n0 + r) * 1024 + k0 + tx] = f2bs(tile[tx][r]);
    }
}

// ---------------- bt-GEMM (templated): C[m][n] = sum_k A[m][k]*Bt[n][k] ----------------
// BMxBN block, 4 waves (2x2), 3-stage global_load_lds pipeline with raw
// s_waitcnt vmcnt(CPW)+s_barrier (never vmcnt(0) mid-loop). XCD-aware 1D grid
// decode: XCD owns an M-strip so its A panel stays L2-hot; B streams once/XCD.
template<int BM, int BN, int NN, int MODE>
__global__ __launch_bounds__(256) void gemm_bt_t(
        const short* __restrict__ A, const short* __restrict__ Bt,
        const float* __restrict__ bq, const float* __restrict__ bk,
        const float* __restrict__ bv, const float* __restrict__ bo,
        short* __restrict__ Qout, short* __restrict__ Kout,
        short* __restrict__ Vtout, float* __restrict__ Cout) {
    const int K = 1024;
    constexpr int ROWS = BM + BN;        // combined A+B panel rows per k-tile
    constexpr int CPW  = ROWS / 64;      // 16-row staging chunks per wave
    constexpr int MBK  = MTOT / BM;      // m-blocks
    constexpr int STRIP = MBK / 8;       // m-tiles per XCD strip
    constexpr int MT = BM / 32, NT = BN / 32;
    __shared__ __align__(16) short S[3][ROWS * 32];

    int tid = threadIdx.x;
    int w = tid >> 6, l = tid & 63, quad = l >> 4, ln = l & 15;
    int wm = w & 1, wn = w >> 1;

    // XCD-aware decode: id%8 ~ XCD; XCD owns M-strip [xcd*STRIP, xcd*STRIP+STRIP)
    int id = blockIdx.x;
    int xcd = id & 7, local = id >> 3;
    int mi = xcd * STRIP + (local % STRIP);
    int ni = local / STRIP;
    int m0 = mi * BM, n0 = ni * BN;

    // staging chunk map: chunk c = w*CPW+j covers panel rows [c*16, c*16+16);
    // panel rows [0,BM) = A tile rows, [BM,ROWS) = B tile rows.
    const short* gsrc[CPW];
    int loff[CPW];
    #pragma unroll
    for (int j = 0; j < CPW; j++) {
        int r0 = (w * CPW + j) * 16;
        int row = r0 + (l >> 2);
        gsrc[j] = (r0 < BM ? A + (size_t)(m0 + row) * K
                           : Bt + (size_t)(n0 + row - BM) * K) + (l & 3) * 8;
        loff[j] = r0 * 32;
    }

    short *sC = &S[0][0], *sN = &S[1][0], *sN2 = &S[2][0];
    #pragma unroll
    for (int j = 0; j < CPW; j++) gload_lds16(gsrc[j], sC + loff[j]);
    #pragma unroll
    for (int j = 0; j < CPW; j++) gload_lds16(gsrc[j] + 32, sN + loff[j]);

    fx4 acc[MT][NT] = {};
    for (int it = 0; it < 32; ++it) {
        if (it < 31) {
            if constexpr (CPW == 4)
                asm volatile("s_waitcnt vmcnt(4)\n\ts_barrier" ::: "memory");
            else
                asm volatile("s_waitcnt vmcnt(3)\n\ts_barrier" ::: "memory");
        } else {
            asm volatile("s_waitcnt vmcnt(0)\n\ts_barrier" ::: "memory");
        }
        if (it < 30) {
            int k0 = (it + 2) * 32;
            #pragma unroll
            for (int j = 0; j < CPW; j++) gload_lds16(gsrc[j] + k0, sN2 + loff[j]);
        }
        bh8 af[MT], bf[NT];
        #pragma unroll
        for (int mt = 0; mt < MT; mt++)
            af[mt] = *(const bh8*)&sC[(wm * (BM / 2) + mt * 16 + ln) * 32 + quad * 8];
        #pragma unroll
        for (int nt = 0; nt < NT; nt++)
            bf[nt] = *(const bh8*)&sC[(BM + wn * (BN / 2) + nt * 16 + ln) * 32 + quad * 8];
        #pragma unroll
        for (int mt = 0; mt < MT; mt++)
            #pragma unroll
            for (int nt = 0; nt < NT; nt++)
                acc[mt][nt] = __builtin_amdgcn_mfma_f32_16x16x32_bf16(af[mt], bf[nt], acc[mt][nt], 0, 0, 0);
        short* t;
        t = sC; sC = sN; sN = sN2; sN2 = t;
    }

    #pragma unroll
    for (int mt = 0; mt < MT; mt++) {
        #pragma unroll
        for (int nt = 0; nt < NT; nt++) {
            int n = n0 + wn * (BN / 2) + nt * 16 + ln;
            int mbase = m0 + wm * (BM / 2) + mt * 16 + quad * 4;
            #pragma unroll
            for (int r = 0; r < 4; r++) {
                float v = acc[mt][nt][r];
                int m = mbase + r;
                if constexpr (MODE == 0) {
                    int which = n >> 10, nn = n & 1023, h = nn >> 6, d = nn & 63;
                    float bias = (which == 0) ? bq[nn] : (which == 1) ? bk[nn] : bv[nn];
                    v += bias;
                    int b = m >> 11, s = m & 2047;
                    if (which == 0)
                        Qout[(((size_t)(b * 16 + h) * 2048) + s) * 64 + d] = f2bs(v * QSCALE);
                    else if (which == 1)
                        Kout[(((size_t)(b * 16 + h) * 2048) + s) * 64 + d] = f2bs(v);
                    else
                        Vtout[((size_t)(b * 16 + h) * 64 + d) * 2048 + s] = f2bs(v);
                } else {
                    Cout[(size_t)m * 1024 + n] = v + bo[n];
                }
            }
        }
    }
}

// ---------------- flash attention: split-K-2, no-max softmax, XCD swizzle ----------------
// v2: (a) P kept fully in-register — swapped-QK layout is converted to the PV
//     B-operand with v_permlane32_swap + v_permlane16_swap (no P LDS round-trip,
//     no mid-iter lgkmcnt stall); (b) K/V double-buffered in LDS (32 KB exactly)
//     staged via global_load_lds DMA with pre-swizzled per-lane global source
//     (linear LDS dest; same XOR involution as the reader); one barrier/iter.
// 1D grid 1024. XCD owns 4 bh -> K/V halves (2MB) stay L2-resident.
// Partials are linear (no max): O_part = sum exp2(s)*V, l_part = sum exp2(s).
__global__ __launch_bounds__(256, 4) void flash_attn(
        const short* __restrict__ Q, const short* __restrict__ Kg,
        const short* __restrict__ Vt,
        float* __restrict__ O0, float* __restrict__ O1,
        float* __restrict__ L0, float* __restrict__ L1) {
    // 32 KB: [K buf0 | K buf1 | V buf0 | V buf1], 4096 shorts each.
    // Epilogue reuses the front 17.4 KB as per-wave fp32 transpose scratch.
    __shared__ __align__(16) short SH[16384];

    int tid = threadIdx.x;
    int w = tid >> 6, l = tid & 63, quad = l >> 4, ln = l & 15;
    // XCD-aware decode: 4 bh per XCD
    int id = blockIdx.x;
    int xcd = id & 7, local = id >> 3;           // local 0..127
    int bh = xcd * 4 + (local & 3);
    int t = local >> 2;                          // 0..31
    int qx = t & 15, z = t >> 4;
    int qblk = qx * 128 + w * 32;
    const short* Qb = Q  + (size_t)bh * 2048 * 64;
    const short* Kb = Kg + (size_t)bh * 2048 * 64 + (size_t)z * 1024 * 64;
    const short* Vb = Vt + (size_t)bh * 64 * 2048 + z * 1024;
    float* Op = z ? O1 : O0;
    float* Lp = z ? L1 : L0;
    int swz = ln & 7;

    // Q fragments (B-operand)
    bh8 qf[2][2];
    #pragma unroll
    for (int qt = 0; qt < 2; qt++)
        #pragma unroll
        for (int c = 0; c < 2; c++)
            qf[qt][c] = *(const bh8*)&Qb[(size_t)(qblk + qt * 16 + ln) * 64 + c * 32 + quad * 8];

    // DMA staging map: 2 chunks K + 2 chunks V per wave; chunk c = w*2+j covers
    // tile rows [c*8, c*8+8). Linear LDS dest: lane l -> short-off c*512 + l*8
    // (row = c*8 + (l>>3), pair p = l&7). Global source pre-swizzled: the lane
    // fetches column-group p ^ (row&7), so LDS[row][p] holds col-group p^(row&7)
    // — exactly what the swizzled ds_read side expects.
    const short* srcK[2]; const short* srcV[2]; int dstoff[2];
    #pragma unroll
    for (int j = 0; j < 2; j++) {
        int c = w * 2 + j;
        int row = c * 8 + (l >> 3);
        int pg = (l & 7) ^ (row & 7);
        srcK[j] = Kb + row * 64 + pg * 8;
        srcV[j] = Vb + (size_t)row * 2048 + pg * 8;
        dstoff[j] = c * 512;
    }

    // prologue: stage tile 0 into buf 0
    #pragma unroll
    for (int j = 0; j < 2; j++) {
        gload_lds16(srcK[j], SH + dstoff[j]);
        gload_lds16(srcV[j], SH + 8192 + dstoff[j]);
    }

    fx4 o[2][4] = {};
    float lpart[2] = {0.f, 0.f};

    for (int it = 0; it < 16; ++it) {
        int koff = (it & 1) ? 4096 : 0;
        // tile `it` DMA complete (own loads) + all waves done reading buf it^1.
        asm volatile("s_waitcnt vmcnt(0) lgkmcnt(0)\n\ts_barrier" ::: "memory");
        if (it < 15) {   // issue next-tile DMA into the other buffer; waited next iter
            int noff = koff ^ 4096;
            int kg = (it + 1) * 4096, vg = (it + 1) * 64;
            #pragma unroll
            for (int j = 0; j < 2; j++) {
                gload_lds16(srcK[j] + kg, SH + noff + dstoff[j]);
                gload_lds16(srcV[j] + vg, SH + 8192 + noff + dstoff[j]);
            }
        }
        const short* ksb = SH + koff;
        const short* vsb = SH + 8192 + koff;

        // S^T[key][q] = K * Q^T
        fx4 s[2][4] = {};
        #pragma unroll
        for (int mt = 0; mt < 4; mt++) {
            bh8 kf0 = *(const bh8*)&ksb[(mt * 16 + ln) * 64 + ((quad ^ swz) * 8)];
            bh8 kf1 = *(const bh8*)&ksb[(mt * 16 + ln) * 64 + (((quad + 4) ^ swz) * 8)];
            #pragma unroll
            for (int qt = 0; qt < 2; qt++) {
                s[qt][mt] = __builtin_amdgcn_mfma_f32_16x16x32_bf16(kf0, qf[qt][0], s[qt][mt], 0, 0, 0);
                s[qt][mt] = __builtin_amdgcn_mfma_f32_16x16x32_bf16(kf1, qf[qt][1], s[qt][mt], 0, 0, 0);
            }
        }

        // P = exp2(S), packed to PV B-fragments entirely in-register.
        // Lane (quad,ln) holds keys {mt*16+quad*4+r} for q=ln; the B-operand
        // needs keys {c2*32+quad*8+j}. With x[mt]=pk(p0,p1), y[mt]=pk(p2,p3):
        //   (u,v)  = permlane32_swap(x[2c2], x[2c2+1])
        //   (D0,D2)= permlane16_swap(u, v)     // keys base+{0,1} / base+4+{0,1}
        // and the y pair gives D1/D3 (keys base+{2,3} / base+4+{2,3}).
        bh8 pf[2][2];
        #pragma unroll
        for (int qt = 0; qt < 2; qt++) {
            float e[4][4];
            #pragma unroll
            for (int mt = 0; mt < 4; mt++) {
                #pragma unroll
                for (int r = 0; r < 4; r++)
                    e[mt][r] = __builtin_amdgcn_exp2f(s[qt][mt][r]);
                lpart[qt] += (e[mt][0] + e[mt][1]) + (e[mt][2] + e[mt][3]);
            }
            #pragma unroll
            for (int c2 = 0; c2 < 2; c2++) {
                unsigned xa = pk_bf16(e[2 * c2][0], e[2 * c2][1]);
                unsigned ya = pk_bf16(e[2 * c2][2], e[2 * c2][3]);
                unsigned xb = pk_bf16(e[2 * c2 + 1][0], e[2 * c2 + 1][1]);
                unsigned yb = pk_bf16(e[2 * c2 + 1][2], e[2 * c2 + 1][3]);
                ux2 u  = __builtin_amdgcn_permlane32_swap(xa, xb, false, false);
                ux2 d02 = __builtin_amdgcn_permlane16_swap(u.x, u.y, false, false);
                ux2 u2 = __builtin_amdgcn_permlane32_swap(ya, yb, false, false);
                ux2 d13 = __builtin_amdgcn_permlane16_swap(u2.x, u2.y, false, false);
                union { unsigned u4[4]; bh8 v; } pk_;
                pk_.u4[0] = d02.x; pk_.u4[1] = d13.x;
                pk_.u4[2] = d02.y; pk_.u4[3] = d13.y;
                pf[qt][c2] = pk_.v;
            }
        }

        // O^T += V^T * P^T
        #pragma unroll
        for (int c2 = 0; c2 < 2; c2++) {
            #pragma unroll
            for (int dt = 0; dt < 4; dt++) {
                bh8 vf = *(const bh8*)&vsb[(dt * 16 + ln) * 64 + (((c2 * 4 + quad) ^ swz) * 8)];
                o[0][dt] = __builtin_amdgcn_mfma_f32_16x16x32_bf16(vf, pf[0][c2], o[0][dt], 0, 0, 0);
                o[1][dt] = __builtin_amdgcn_mfma_f32_16x16x32_bf16(vf, pf[1][c2], o[1][dt], 0, 0, 0);
            }
        }
    }

    // all waves done reading K/V LDS before reusing it as epilogue scratch
    asm volatile("s_waitcnt lgkmcnt(0)\n\ts_barrier" ::: "memory");

    // epilogue: fp32 partials O^T -> O via per-wave LDS transpose, + l partials.
    float* PsF = (float*)SH + w * 1088;   // 16 rows x 68-float stride, 4352 B/wave
    int row = l >> 2, seg = l & 3;
    #pragma unroll
    for (int qt = 0; qt < 2; qt++) {
        #pragma unroll
        for (int dt = 0; dt < 4; dt++)
            *(fx4*)&PsF[ln * 68 + dt * 16 + quad * 4] = o[qt][dt];
        asm volatile("s_waitcnt lgkmcnt(0)" ::: "memory");
        float* orow = &Op[((size_t)bh * 2048 + qblk + qt * 16 + row) * 64];
        #pragma unroll
        for (int j = 0; j < 4; j++) {
            fx4 v = *(fx4*)&PsF[row * 68 + seg * 16 + j * 4];
            *(fx4*)&orow[seg * 16 + j * 4] = v;
        }
        asm volatile("s_waitcnt lgkmcnt(0)" ::: "memory");
        float lr = lpart[qt];
        lr += __shfl_xor(lr, 16);
        lr += __shfl_xor(lr, 32);
        if (l < 16) Lp[(size_t)bh * 2048 + qblk + qt * 16 + l] = lr;
    }
}

// ---------------- combine: Ctx = (O0+O1)/(L0+L1), bf16 ----------------
__global__ __launch_bounds__(256) void combine(
        const float* __restrict__ O0, const float* __restrict__ O1,
        const float* __restrict__ L0, const float* __restrict__ L1,
        short* __restrict__ Ctx) {
    int t = blockIdx.x * 256 + threadIdx.x;        // 524288 threads, 8 floats each
    size_t base = (size_t)t * 8;
    int bhq = t >> 3;
    int d = (t & 7) * 8;
    int bh = bhq >> 11, q = bhq & 2047;
    int b = bh >> 4, h = bh & 15;
    float inv = 1.0f / (L0[bhq] + L1[bhq]);
    float4 a0 = *(const float4*)(O0 + base);
    float4 a1 = *(const float4*)(O0 + base + 4);
    float4 c0 = *(const float4*)(O1 + base);
    float4 c1 = *(const float4*)(O1 + base + 4);
    union { short s[8]; bh8 v; } o;
    o.s[0] = f2bs((a0.x + c0.x) * inv); o.s[1] = f2bs((a0.y + c0.y) * inv);
    o.s[2] = f2bs((a0.z + c0.z) * inv); o.s[3] = f2bs((a0.w + c0.w) * inv);
    o.s[4] = f2bs((a1.x + c1.x) * inv); o.s[5] = f2bs((a1.y + c1.y) * inv);
    o.s[6] = f2bs((a1.z + c1.z) * inv); o.s[7] = f2bs((a1.w + c1.w) * inv);
    *(bh8*)&Ctx[((size_t)(b * 2048 + q)) * 1024 + h * 64 + d] = o.v;
}

extern "C" void kernel_launch(void* const* d_in, const int* in_sizes, int n_in,
                              void* d_out, int out_size, void* d_ws, size_t ws_size,
                              hipStream_t stream) {
    const float* emb = (const float*)d_in[0];
    const float* Wq  = (const float*)d_in[1];
    const float* bq  = (const float*)d_in[2];
    const float* Wk  = (const float*)d_in[3];
    const float* bk  = (const float*)d_in[4];
    const float* Wv  = (const float*)d_in[5];
    const float* bv  = (const float*)d_in[6];
    const float* Wo  = (const float*)d_in[7];
    const float* bo  = (const float*)d_in[8];

    char* ws = (char*)d_ws;
    const size_t MB = 1024 * 1024;
    short* Xbf  = (short*)(ws + 0);
    short* Wt   = (short*)(ws + 8 * MB);
    float* Op1  = (float*)(ws + 0);          // flash partial z=1 (reuses Xbf/Wt)
    short* Wot  = (short*)(ws + 17 * MB);
    short* Qb   = (short*)(ws + 19 * MB);    // pre-scaled by QSCALE
    short* Ctx  = (short*)(ws + 19 * MB);    // overlays Qb (combine after flash)
    short* Kb   = (short*)(ws + 27 * MB);
    short* Vtb  = (short*)(ws + 35 * MB);    // [B,H,Dh,S]
    float* L0   = (float*)(ws + 43 * MB);
    float* L1   = (float*)(ws + 43 * MB + 256 * 1024);
    float* Op0  = (float*)d_out;             // flash partial z=0 (d_out as scratch,
                                             // fully overwritten by final gemm)

    cvt_emb<<<4096, 256, 0, stream>>>(emb, Xbf, MTOT * DMODEL);
    transpose_w<<<dim3(16, 16, 4), dim3(64, 4), 0, stream>>>(Wq, Wk, Wv, Wo, Wt, Wot);
    // QKV projection: 128x128 tiles, 32x24 = 768 blocks, XCD-swizzled
    gemm_bt_t<128, 128, NQKV, 0><<<768, 256, 0, stream>>>(
        Xbf, Wt, bq, bk, bv, nullptr, Qb, Kb, Vtb, nullptr);
    flash_attn<<<1024, 256, 0, stream>>>(Qb, Kb, Vtb, Op0, Op1, L0, L1);
    combine<<<2048, 256, 0, stream>>>(Op0, Op1, L0, L1, Ctx);
    // output projection: 64x128 tiles, 64x8 = 512 blocks, XCD-swizzled
    gemm_bt_t<64, 128, DMODEL, 1><<<512, 256, 0, stream>>>(
        Ctx, Wot, nullptr, nullptr, nullptr, bo, nullptr, nullptr, nullptr, (float*)d_out);
}

// Round 2
// 201.718 us; speedup vs baseline: 1.0453x; 1.0343x over previous
//
#include <hip/hip_runtime.h>
#include <hip/hip_bf16.h>

// ---- problem constants ----
#define BB 2
#define SS 2048
#define DMODEL 1024
#define NHEADS 16
#define DHEAD 64
#define MTOT (BB*SS)      // 4096
#define NQKV 3072
#define QSCALE 0.18033688011112042f   // 0.125 * log2(e), folded into Q at projection

typedef short bh8 __attribute__((ext_vector_type(8)));   // 8 bf16 (4 VGPRs)
typedef float fx4 __attribute__((ext_vector_type(4)));   // MFMA accumulator
typedef unsigned int ux2 __attribute__((ext_vector_type(2)));

__device__ __forceinline__ short f2bs(float f) {
    __hip_bfloat16 h = __float2bfloat16(f);
    return *reinterpret_cast<short*>(&h);
}

__device__ __forceinline__ unsigned pk_bf16(float a, float b) {
    __hip_bfloat162 h = __float22bfloat162_rn(make_float2(a, b));
    return *reinterpret_cast<unsigned*>(&h);
}

// async global->LDS, 16B per lane. LDS dest wave-uniform base + lane*16.
__device__ __forceinline__ void gload_lds16(const short* g, short* l) {
    __builtin_amdgcn_global_load_lds(
        (const __attribute__((address_space(1))) unsigned int*)g,
        (__attribute__((address_space(3))) unsigned int*)l, 16, 0, 0);
}

// ---------------- prep: fp32 -> bf16 elementwise ----------------
__global__ __launch_bounds__(256) void cvt_emb(const float* __restrict__ x,
                                               short* __restrict__ y, int n) {
    int i = (blockIdx.x * 256 + threadIdx.x) * 4;
    if (i + 3 < n) {
        float4 v = *(const float4*)(x + i);
        short4 o;
        o.x = f2bs(v.x); o.y = f2bs(v.y); o.z = f2bs(v.z); o.w = f2bs(v.w);
        *(short4*)(y + i) = o;
    }
}

// ------------- prep: transpose + convert weights (1024x1024 each) -------------
__global__ __launch_bounds__(256) void transpose_w(
        const float* __restrict__ Wq, const float* __restrict__ Wk,
        const float* __restrict__ Wv, const float* __restrict__ Wo,
        short* __restrict__ Wt_qkv, short* __restrict__ Wot) {
    __shared__ float tile[64][65];
    int z = blockIdx.z;
    const float* src = (z == 0) ? Wq : (z == 1) ? Wk : (z == 2) ? Wv : Wo;
    short* dst = (z == 3) ? Wot : (Wt_qkv + (size_t)z * 1024 * 1024);
    int n0 = blockIdx.x * 64, k0 = blockIdx.y * 64;
    int tx = threadIdx.x, ty = threadIdx.y;
    for (int j = 0; j < 16; j++) {
        int r = ty + j * 4;
        tile[r][tx] = src[(size_t)(k0 + r) * 1024 + n0 + tx];
    }
    __syncthreads();
    for (int j = 0; j < 16; j++) {
        int r = ty + j * 4;
        dst[(size_t)(n0 + r) * 1024 + k0 + tx] = f2bs(tile[tx][r]);
    }
}

// ---------------- bt-GEMM (templated): C[m][n] = sum_k A[m][k]*Bt[n][k] ----------------
// BMxBN block, 4 waves (2x2), 3-stage global_load_lds pipeline with raw
// s_waitcnt vmcnt(CPW)+s_barrier (never vmcnt(0) mid-loop). XCD-aware 1D grid
// decode: XCD owns an M-strip so its A panel stays L2-hot; B streams once/XCD.
template<int BM, int BN, int NN, int MODE>
__global__ __launch_bounds__(256) void gemm_bt_t(
        const short* __restrict__ A, const short* __restrict__ Bt,
        const float* __restrict__ bq, const float* __restrict__ bk,
        const float* __restrict__ bv, const float* __restrict__ bo,
        short* __restrict__ Qout, short* __restrict__ Kout,
        short* __restrict__ Vtout, float* __restrict__ Cout) {
    const int K = 1024;
    constexpr int ROWS = BM + BN;        // combined A+B panel rows per k-tile
    constexpr int CPW  = ROWS / 64;      // 16-row staging chunks per wave
    constexpr int MBK  = MTOT / BM;      // m-blocks
    constexpr int STRIP = MBK / 8;       // m-tiles per XCD strip
    constexpr int MT = BM / 32, NT = BN / 32;
    __shared__ __align__(16) short S[3][ROWS * 32];

    int tid = threadIdx.x;
    int w = tid >> 6, l = tid & 63, quad = l >> 4, ln = l & 15;
    int wm = w & 1, wn = w >> 1;

    // XCD-aware decode: id%8 ~ XCD; XCD owns M-strip [xcd*STRIP, xcd*STRIP+STRIP)
    int id = blockIdx.x;
    int xcd = id & 7, local = id >> 3;
    int mi = xcd * STRIP + (local % STRIP);
    int ni = local / STRIP;
    int m0 = mi * BM, n0 = ni * BN;

    // staging chunk map: chunk c = w*CPW+j covers panel rows [c*16, c*16+16);
    // panel rows [0,BM) = A tile rows, [BM,ROWS) = B tile rows.
    const short* gsrc[CPW];
    int loff[CPW];
    #pragma unroll
    for (int j = 0; j < CPW; j++) {
        int r0 = (w * CPW + j) * 16;
        int row = r0 + (l >> 2);
        gsrc[j] = (r0 < BM ? A + (size_t)(m0 + row) * K
                           : Bt + (size_t)(n0 + row - BM) * K) + (l & 3) * 8;
        loff[j] = r0 * 32;
    }

    short *sC = &S[0][0], *sN = &S[1][0], *sN2 = &S[2][0];
    #pragma unroll
    for (int j = 0; j < CPW; j++) gload_lds16(gsrc[j], sC + loff[j]);
    #pragma unroll
    for (int j = 0; j < CPW; j++) gload_lds16(gsrc[j] + 32, sN + loff[j]);

    fx4 acc[MT][NT] = {};
    for (int it = 0; it < 32; ++it) {
        if (it < 31) {
            if constexpr (CPW == 4)
                asm volatile("s_waitcnt vmcnt(4)\n\ts_barrier" ::: "memory");
            else
                asm volatile("s_waitcnt vmcnt(3)\n\ts_barrier" ::: "memory");
        } else {
            asm volatile("s_waitcnt vmcnt(0)\n\ts_barrier" ::: "memory");
        }
        if (it < 30) {
            int k0 = (it + 2) * 32;
            #pragma unroll
            for (int j = 0; j < CPW; j++) gload_lds16(gsrc[j] + k0, sN2 + loff[j]);
        }
        bh8 af[MT], bf[NT];
        #pragma unroll
        for (int mt = 0; mt < MT; mt++)
            af[mt] = *(const bh8*)&sC[(wm * (BM / 2) + mt * 16 + ln) * 32 + quad * 8];
        #pragma unroll
        for (int nt = 0; nt < NT; nt++)
            bf[nt] = *(const bh8*)&sC[(BM + wn * (BN / 2) + nt * 16 + ln) * 32 + quad * 8];
        #pragma unroll
        for (int mt = 0; mt < MT; mt++)
            #pragma unroll
            for (int nt = 0; nt < NT; nt++)
                acc[mt][nt] = __builtin_amdgcn_mfma_f32_16x16x32_bf16(af[mt], bf[nt], acc[mt][nt], 0, 0, 0);
        short* t;
        t = sC; sC = sN; sN = sN2; sN2 = t;
    }

    #pragma unroll
    for (int mt = 0; mt < MT; mt++) {
        #pragma unroll
        for (int nt = 0; nt < NT; nt++) {
            int n = n0 + wn * (BN / 2) + nt * 16 + ln;
            int mbase = m0 + wm * (BM / 2) + mt * 16 + quad * 4;
            #pragma unroll
            for (int r = 0; r < 4; r++) {
                float v = acc[mt][nt][r];
                int m = mbase + r;
                if constexpr (MODE == 0) {
                    int which = n >> 10, nn = n & 1023, h = nn >> 6, d = nn & 63;
                    float bias = (which == 0) ? bq[nn] : (which == 1) ? bk[nn] : bv[nn];
                    v += bias;
                    int b = m >> 11, s = m & 2047;
                    if (which == 0)
                        Qout[(((size_t)(b * 16 + h) * 2048) + s) * 64 + d] = f2bs(v * QSCALE);
                    else if (which == 1)
                        Kout[(((size_t)(b * 16 + h) * 2048) + s) * 64 + d] = f2bs(v);
                    else
                        Vtout[((size_t)(b * 16 + h) * 64 + d) * 2048 + s] = f2bs(v);
                } else {
                    Cout[(size_t)m * 1024 + n] = v + bo[n];
                }
            }
        }
    }
}

// ---------------- flash attention: no split-K, fused 1/l + bf16 output ----------------
// v3: (a) split-K removed — each block walks all 32 K/V tiles; epilogue divides
//     by l and writes bf16 Ctx directly (combine kernel + 33 MB fp32 partial
//     traffic eliminated); (b) 3-stage DMA pipeline with counted vmcnt(4) —
//     never drains to 0 mid-loop, each tile's DMA gets 2 compute phases.
// Grid 512 = exactly 2 blocks/CU, one round. XCD owns 4 bh -> K/V (2 MB) L2-hot.
__global__ __launch_bounds__(256, 4) void flash_attn(
        const short* __restrict__ Q, const short* __restrict__ Kg,
        const short* __restrict__ Vt, short* __restrict__ Ctx) {
    // 48 KB: 3 K bufs (8 KB each) + 3 V bufs. Epilogue reuses front 17.4 KB.
    __shared__ __align__(16) short SH[24576];

    int tid = threadIdx.x;
    int w = tid >> 6, l = tid & 63, quad = l >> 4, ln = l & 15;
    // XCD-aware decode: 4 bh per XCD
    int id = blockIdx.x;
    int xcd = id & 7, local = id >> 3;           // local 0..63
    int bh = xcd * 4 + (local & 3);
    int qx = local >> 2;                         // 0..15
    int qblk = qx * 128 + w * 32;
    int b = bh >> 4, h = bh & 15;
    const short* Qb = Q  + (size_t)bh * 2048 * 64;
    const short* Kb = Kg + (size_t)bh * 2048 * 64;
    const short* Vb = Vt + (size_t)bh * 64 * 2048;
    int swz = ln & 7;

    // Q fragments (B-operand)
    bh8 qf[2][2];
    #pragma unroll
    for (int qt = 0; qt < 2; qt++)
        #pragma unroll
        for (int c = 0; c < 2; c++)
            qf[qt][c] = *(const bh8*)&Qb[(size_t)(qblk + qt * 16 + ln) * 64 + c * 32 + quad * 8];

    // DMA staging map: 2 chunks K + 2 chunks V per wave; chunk c = w*2+j covers
    // tile rows [c*8, c*8+8). Linear LDS dest: lane l -> short-off c*512 + l*8
    // (row = c*8 + (l>>3), pair p = l&7). Global source pre-swizzled so
    // LDS[row][p] holds col-group p^(row&7) — matching the swizzled reads.
    const short* srcK[2]; const short* srcV[2]; int dstoff[2];
    #pragma unroll
    for (int j = 0; j < 2; j++) {
        int c = w * 2 + j;
        int row = c * 8 + (l >> 3);
        int pg = (l & 7) ^ (row & 7);
        srcK[j] = Kb + row * 64 + pg * 8;
        srcV[j] = Vb + (size_t)row * 2048 + pg * 8;
        dstoff[j] = c * 512;
    }

    // 3-buffer rotation (short offsets into SH)
    int kb0 = 0, kb1 = 4096, kb2 = 8192;
    int vb0 = 12288, vb1 = 16384, vb2 = 20480;

    // prologue: tile 0 -> buf0, tile 1 -> buf1 (8 DMAs outstanding)
    #pragma unroll
    for (int j = 0; j < 2; j++) {
        gload_lds16(srcK[j], SH + kb0 + dstoff[j]);
        gload_lds16(srcV[j], SH + vb0 + dstoff[j]);
    }
    #pragma unroll
    for (int j = 0; j < 2; j++) {
        gload_lds16(srcK[j] + 4096, SH + kb1 + dstoff[j]);
        gload_lds16(srcV[j] + 64,   SH + vb1 + dstoff[j]);
    }

    fx4 o[2][4] = {};
    float lpart[2] = {0.f, 0.f};

    for (int it = 0; it < 32; ++it) {
        // drain this tile's 4 DMAs (leave next tile's 4 in flight); sync waves.
        if (it < 31)
            asm volatile("s_waitcnt vmcnt(4) lgkmcnt(0)\n\ts_barrier" ::: "memory");
        else
            asm volatile("s_waitcnt vmcnt(0) lgkmcnt(0)\n\ts_barrier" ::: "memory");
        if (it < 30) {   // prefetch tile it+2 into the just-freed buffer
            int kg = (it + 2) * 4096, vg = (it + 2) * 64;
            #pragma unroll
            for (int j = 0; j < 2; j++) {
                gload_lds16(srcK[j] + kg, SH + kb2 + dstoff[j]);
                gload_lds16(srcV[j] + vg, SH + vb2 + dstoff[j]);
            }
        }
        const short* ksb = SH + kb0;
        const short* vsb = SH + vb0;

        // S^T[key][q] = K * Q^T
        fx4 s[2][4] = {};
        #pragma unroll
        for (int mt = 0; mt < 4; mt++) {
            bh8 kf0 = *(const bh8*)&ksb[(mt * 16 + ln) * 64 + ((quad ^ swz) * 8)];
            bh8 kf1 = *(const bh8*)&ksb[(mt * 16 + ln) * 64 + (((quad + 4) ^ swz) * 8)];
            #pragma unroll
            for (int qt = 0; qt < 2; qt++) {
                s[qt][mt] = __builtin_amdgcn_mfma_f32_16x16x32_bf16(kf0, qf[qt][0], s[qt][mt], 0, 0, 0);
                s[qt][mt] = __builtin_amdgcn_mfma_f32_16x16x32_bf16(kf1, qf[qt][1], s[qt][mt], 0, 0, 0);
            }
        }

        // P = exp2(S), packed to PV B-fragments entirely in-register
        // (permlane32_swap + permlane16_swap redistribute the C-layout quads).
        bh8 pf[2][2];
        #pragma unroll
        for (int qt = 0; qt < 2; qt++) {
            float e[4][4];
            #pragma unroll
            for (int mt = 0; mt < 4; mt++) {
                #pragma unroll
                for (int r = 0; r < 4; r++)
                    e[mt][r] = __builtin_amdgcn_exp2f(s[qt][mt][r]);
                lpart[qt] += (e[mt][0] + e[mt][1]) + (e[mt][2] + e[mt][3]);
            }
            #pragma unroll
            for (int c2 = 0; c2 < 2; c2++) {
                unsigned xa = pk_bf16(e[2 * c2][0], e[2 * c2][1]);
                unsigned ya = pk_bf16(e[2 * c2][2], e[2 * c2][3]);
                unsigned xb = pk_bf16(e[2 * c2 + 1][0], e[2 * c2 + 1][1]);
                unsigned yb = pk_bf16(e[2 * c2 + 1][2], e[2 * c2 + 1][3]);
                ux2 u  = __builtin_amdgcn_permlane32_swap(xa, xb, false, false);
                ux2 d02 = __builtin_amdgcn_permlane16_swap(u.x, u.y, false, false);
                ux2 u2 = __builtin_amdgcn_permlane32_swap(ya, yb, false, false);
                ux2 d13 = __builtin_amdgcn_permlane16_swap(u2.x, u2.y, false, false);
                union { unsigned u4[4]; bh8 v; } pk_;
                pk_.u4[0] = d02.x; pk_.u4[1] = d13.x;
                pk_.u4[2] = d02.y; pk_.u4[3] = d13.y;
                pf[qt][c2] = pk_.v;
            }
        }

        // O^T += V^T * P^T
        #pragma unroll
        for (int c2 = 0; c2 < 2; c2++) {
            #pragma unroll
            for (int dt = 0; dt < 4; dt++) {
                bh8 vf = *(const bh8*)&vsb[(dt * 16 + ln) * 64 + (((c2 * 4 + quad) ^ swz) * 8)];
                o[0][dt] = __builtin_amdgcn_mfma_f32_16x16x32_bf16(vf, pf[0][c2], o[0][dt], 0, 0, 0);
                o[1][dt] = __builtin_amdgcn_mfma_f32_16x16x32_bf16(vf, pf[1][c2], o[1][dt], 0, 0, 0);
            }
        }

        int t0_;
        t0_ = kb0; kb0 = kb1; kb1 = kb2; kb2 = t0_;
        t0_ = vb0; vb0 = vb1; vb1 = vb2; vb2 = t0_;
    }

    // all waves done reading K/V LDS before reusing it as epilogue scratch
    asm volatile("s_waitcnt vmcnt(0) lgkmcnt(0)\n\ts_barrier" ::: "memory");

    // epilogue: O^T -> rows via per-wave LDS transpose, scale by 1/l, bf16 out.
    float* PsF = (float*)SH + w * 1088;   // 16 rows x 68-float stride, 4352 B/wave
    int row = l >> 2, seg = l & 3;
    #pragma unroll
    for (int qt = 0; qt < 2; qt++) {
        #pragma unroll
        for (int dt = 0; dt < 4; dt++)
            *(fx4*)&PsF[ln * 68 + dt * 16 + quad * 4] = o[qt][dt];
        asm volatile("s_waitcnt lgkmcnt(0)" ::: "memory");
        float lr = lpart[qt];
        lr += __shfl_xor(lr, 16);
        lr += __shfl_xor(lr, 32);
        float invr = __shfl(1.0f / lr, row);       // lane `row` holds l for q-row `row`
        int q = qblk + qt * 16 + row;
        short* crow = Ctx + ((size_t)(b * 2048 + q)) * 1024 + h * 64 + seg * 16;
        union { short s[8]; uint4 u; } o0, o1;
        #pragma unroll
        for (int j = 0; j < 2; j++) {
            fx4 v = *(fx4*)&PsF[row * 68 + seg * 16 + j * 4];
            o0.s[j * 4 + 0] = f2bs(v[0] * invr);
            o0.s[j * 4 + 1] = f2bs(v[1] * invr);
            o0.s[j * 4 + 2] = f2bs(v[2] * invr);
            o0.s[j * 4 + 3] = f2bs(v[3] * invr);
        }
        #pragma unroll
        for (int j = 2; j < 4; j++) {
            fx4 v = *(fx4*)&PsF[row * 68 + seg * 16 + j * 4];
            o1.s[(j - 2) * 4 + 0] = f2bs(v[0] * invr);
            o1.s[(j - 2) * 4 + 1] = f2bs(v[1] * invr);
            o1.s[(j - 2) * 4 + 2] = f2bs(v[2] * invr);
            o1.s[(j - 2) * 4 + 3] = f2bs(v[3] * invr);
        }
        *(uint4*)&crow[0] = o0.u;
        *(uint4*)&crow[8] = o1.u;
        asm volatile("s_waitcnt lgkmcnt(0)" ::: "memory");  // reads done before next qt overwrites
    }
}

extern "C" void kernel_launch(void* const* d_in, const int* in_sizes, int n_in,
                              void* d_out, int out_size, void* d_ws, size_t ws_size,
                              hipStream_t stream) {
    const float* emb = (const float*)d_in[0];
    const float* Wq  = (const float*)d_in[1];
    const float* bq  = (const float*)d_in[2];
    const float* Wk  = (const float*)d_in[3];
    const float* bk  = (const float*)d_in[4];
    const float* Wv  = (const float*)d_in[5];
    const float* bv  = (const float*)d_in[6];
    const float* Wo  = (const float*)d_in[7];
    const float* bo  = (const float*)d_in[8];

    char* ws = (char*)d_ws;
    const size_t MB = 1024 * 1024;
    short* Xbf  = (short*)(ws + 0);          // A panel for QKV gemm
    short* Ctx  = (short*)(ws + 0);          // flash bf16 output (overlays Xbf,
                                             // which is dead after the QKV gemm)
    short* Wt   = (short*)(ws + 8 * MB);
    short* Wot  = (short*)(ws + 17 * MB);
    short* Qb   = (short*)(ws + 19 * MB);    // pre-scaled by QSCALE
    short* Kb   = (short*)(ws + 27 * MB);
    short* Vtb  = (short*)(ws + 35 * MB);    // [B,H,Dh,S]

    cvt_emb<<<4096, 256, 0, stream>>>(emb, Xbf, MTOT * DMODEL);
    transpose_w<<<dim3(16, 16, 4), dim3(64, 4), 0, stream>>>(Wq, Wk, Wv, Wo, Wt, Wot);
    // QKV projection: 128x128 tiles, 32x24 = 768 blocks, XCD-swizzled
    gemm_bt_t<128, 128, NQKV, 0><<<768, 256, 0, stream>>>(
        Xbf, Wt, bq, bk, bv, nullptr, Qb, Kb, Vtb, nullptr);
    // attention (no split-K): 512 blocks = 2/CU, writes bf16 Ctx directly
    flash_attn<<<512, 256, 0, stream>>>(Qb, Kb, Vtb, Ctx);
    // output projection: 64x128 tiles, 64x8 = 512 blocks, XCD-swizzled
    gemm_bt_t<64, 128, DMODEL, 1><<<512, 256, 0, stream>>>(
        Ctx, Wot, nullptr, nullptr, nullptr, bo, nullptr, nullptr, nullptr, (float*)d_out);
}

// Round 3
// 201.372 us; speedup vs baseline: 1.0471x; 1.0017x over previous
//
#include <hip/hip_runtime.h>
#include <hip/hip_bf16.h>

// ---- problem constants ----
#define BB 2
#define SS 2048
#define DMODEL 1024
#define NHEADS 16
#define DHEAD 64
#define MTOT (BB*SS)      // 4096
#define NQKV 3072
#define QSCALE 0.18033688011112042f   // 0.125 * log2(e), folded into Q at projection

typedef short bh8 __attribute__((ext_vector_type(8)));   // 8 bf16 (4 VGPRs)
typedef float fx4 __attribute__((ext_vector_type(4)));   // MFMA accumulator
typedef unsigned int ux2 __attribute__((ext_vector_type(2)));

__device__ __forceinline__ short f2bs(float f) {
    __hip_bfloat16 h = __float2bfloat16(f);
    return *reinterpret_cast<short*>(&h);
}

__device__ __forceinline__ unsigned pk_bf16(float a, float b) {
    __hip_bfloat162 h = __float22bfloat162_rn(make_float2(a, b));
    return *reinterpret_cast<unsigned*>(&h);
}

// async global->LDS, 16B per lane. LDS dest wave-uniform base + lane*16.
__device__ __forceinline__ void gload_lds16(const short* g, short* l) {
    __builtin_amdgcn_global_load_lds(
        (const __attribute__((address_space(1))) unsigned int*)g,
        (__attribute__((address_space(3))) unsigned int*)l, 16, 0, 0);
}

// ---------------- prep: fp32 -> bf16 elementwise ----------------
__global__ __launch_bounds__(256) void cvt_emb(const float* __restrict__ x,
                                               short* __restrict__ y, int n) {
    int i = (blockIdx.x * 256 + threadIdx.x) * 4;
    if (i + 3 < n) {
        float4 v = *(const float4*)(x + i);
        short4 o;
        o.x = f2bs(v.x); o.y = f2bs(v.y); o.z = f2bs(v.z); o.w = f2bs(v.w);
        *(short4*)(y + i) = o;
    }
}

// ------------- prep: transpose + convert weights (1024x1024 each) -------------
__global__ __launch_bounds__(256) void transpose_w(
        const float* __restrict__ Wq, const float* __restrict__ Wk,
        const float* __restrict__ Wv, const float* __restrict__ Wo,
        short* __restrict__ Wt_qkv, short* __restrict__ Wot) {
    __shared__ float tile[64][65];
    int z = blockIdx.z;
    const float* src = (z == 0) ? Wq : (z == 1) ? Wk : (z == 2) ? Wv : Wo;
    short* dst = (z == 3) ? Wot : (Wt_qkv + (size_t)z * 1024 * 1024);
    int n0 = blockIdx.x * 64, k0 = blockIdx.y * 64;
    int tx = threadIdx.x, ty = threadIdx.y;
    for (int j = 0; j < 16; j++) {
        int r = ty + j * 4;
        tile[r][tx] = src[(size_t)(k0 + r) * 1024 + n0 + tx];
    }
    __syncthreads();
    for (int j = 0; j < 16; j++) {
        int r = ty + j * 4;
        dst[(size_t)(n0 + r) * 1024 + k0 + tx] = f2bs(tile[tx][r]);
    }
}

// ---------------- bt-GEMM (templated): C[m][n] = sum_k A[m][k]*Bt[n][k] ----------------
// BMxBN block, 4 waves (2x2), 3-stage global_load_lds pipeline with raw
// s_waitcnt vmcnt(CPW)+s_barrier (never vmcnt(0) mid-loop). XCD-aware 1D grid
// decode: XCD owns an M-strip so its A panel stays L2-hot; B streams once/XCD.
template<int BM, int BN, int NN, int MODE>
__global__ __launch_bounds__(256) void gemm_bt_t(
        const short* __restrict__ A, const short* __restrict__ Bt,
        const float* __restrict__ bq, const float* __restrict__ bk,
        const float* __restrict__ bv, const float* __restrict__ bo,
        short* __restrict__ Qout, short* __restrict__ Kout,
        short* __restrict__ Vtout, float* __restrict__ Cout) {
    const int K = 1024;
    constexpr int ROWS = BM + BN;        // combined A+B panel rows per k-tile
    constexpr int CPW  = ROWS / 64;      // 16-row staging chunks per wave
    constexpr int MBK  = MTOT / BM;      // m-blocks
    constexpr int STRIP = MBK / 8;       // m-tiles per XCD strip
    constexpr int MT = BM / 32, NT = BN / 32;
    __shared__ __align__(16) short S[3][ROWS * 32];

    int tid = threadIdx.x;
    int w = tid >> 6, l = tid & 63, quad = l >> 4, ln = l & 15;
    int wm = w & 1, wn = w >> 1;

    // XCD-aware decode: id%8 ~ XCD; XCD owns M-strip [xcd*STRIP, xcd*STRIP+STRIP)
    int id = blockIdx.x;
    int xcd = id & 7, local = id >> 3;
    int mi = xcd * STRIP + (local % STRIP);
    int ni = local / STRIP;
    int m0 = mi * BM, n0 = ni * BN;

    // staging chunk map: chunk c = w*CPW+j covers panel rows [c*16, c*16+16);
    // panel rows [0,BM) = A tile rows, [BM,ROWS) = B tile rows.
    const short* gsrc[CPW];
    int loff[CPW];
    #pragma unroll
    for (int j = 0; j < CPW; j++) {
        int r0 = (w * CPW + j) * 16;
        int row = r0 + (l >> 2);
        gsrc[j] = (r0 < BM ? A + (size_t)(m0 + row) * K
                           : Bt + (size_t)(n0 + row - BM) * K) + (l & 3) * 8;
        loff[j] = r0 * 32;
    }

    short *sC = &S[0][0], *sN = &S[1][0], *sN2 = &S[2][0];
    #pragma unroll
    for (int j = 0; j < CPW; j++) gload_lds16(gsrc[j], sC + loff[j]);
    #pragma unroll
    for (int j = 0; j < CPW; j++) gload_lds16(gsrc[j] + 32, sN + loff[j]);

    fx4 acc[MT][NT] = {};
    for (int it = 0; it < 32; ++it) {
        if (it < 31) {
            if constexpr (CPW == 4)
                asm volatile("s_waitcnt vmcnt(4)\n\ts_barrier" ::: "memory");
            else
                asm volatile("s_waitcnt vmcnt(3)\n\ts_barrier" ::: "memory");
        } else {
            asm volatile("s_waitcnt vmcnt(0)\n\ts_barrier" ::: "memory");
        }
        if (it < 30) {
            int k0 = (it + 2) * 32;
            #pragma unroll
            for (int j = 0; j < CPW; j++) gload_lds16(gsrc[j] + k0, sN2 + loff[j]);
        }
        bh8 af[MT], bf[NT];
        #pragma unroll
        for (int mt = 0; mt < MT; mt++)
            af[mt] = *(const bh8*)&sC[(wm * (BM / 2) + mt * 16 + ln) * 32 + quad * 8];
        #pragma unroll
        for (int nt = 0; nt < NT; nt++)
            bf[nt] = *(const bh8*)&sC[(BM + wn * (BN / 2) + nt * 16 + ln) * 32 + quad * 8];
        #pragma unroll
        for (int mt = 0; mt < MT; mt++)
            #pragma unroll
            for (int nt = 0; nt < NT; nt++)
                acc[mt][nt] = __builtin_amdgcn_mfma_f32_16x16x32_bf16(af[mt], bf[nt], acc[mt][nt], 0, 0, 0);
        short* t;
        t = sC; sC = sN; sN = sN2; sN2 = t;
    }

    #pragma unroll
    for (int mt = 0; mt < MT; mt++) {
        #pragma unroll
        for (int nt = 0; nt < NT; nt++) {
            int n = n0 + wn * (BN / 2) + nt * 16 + ln;
            int mbase = m0 + wm * (BM / 2) + mt * 16 + quad * 4;
            #pragma unroll
            for (int r = 0; r < 4; r++) {
                float v = acc[mt][nt][r];
                int m = mbase + r;
                if constexpr (MODE == 0) {
                    int which = n >> 10, nn = n & 1023, h = nn >> 6, d = nn & 63;
                    float bias = (which == 0) ? bq[nn] : (which == 1) ? bk[nn] : bv[nn];
                    v += bias;
                    int b = m >> 11, s = m & 2047;
                    if (which == 0)
                        Qout[(((size_t)(b * 16 + h) * 2048) + s) * 64 + d] = f2bs(v * QSCALE);
                    else if (which == 1)
                        Kout[(((size_t)(b * 16 + h) * 2048) + s) * 64 + d] = f2bs(v);
                    else
                        Vtout[((size_t)(b * 16 + h) * 64 + d) * 2048 + s] = f2bs(v);
                } else {
                    Cout[(size_t)m * 1024 + n] = v + bo[n];
                }
            }
        }
    }
}

// ---------------- flash attention: Q-split, fused 1/l + bf16 output ----------------
// v4: split over Q instead of K — 1024 blocks, each owns 64 q-rows (4 waves x
// 16 rows) and walks all 32 K/V tiles. Keeps the fused epilogue (no combine,
// no fp32 partials) AND restores round-1 parallelism: 32 KB LDS, 2-stage DMA
// double-buffer -> 4 blocks/CU = 16 waves/CU. Per-wave state halves (VGPR ~65).
// XCD owns 4 bh -> K/V (2 MB) L2-hot; K/V re-staged 8x per bh, all L2 hits.
__global__ __launch_bounds__(256, 4) void flash_attn(
        const short* __restrict__ Q, const short* __restrict__ Kg,
        const short* __restrict__ Vt, short* __restrict__ Ctx) {
    // 32 KB: [K buf0 | K buf1 | V buf0 | V buf1], 4096 shorts each.
    // Epilogue reuses the front 17.4 KB as per-wave fp32 transpose scratch.
    __shared__ __align__(16) short SH[16384];

    int tid = threadIdx.x;
    int w = tid >> 6, l = tid & 63, quad = l >> 4, ln = l & 15;
    // XCD-aware decode: 4 bh per XCD, 32 q-blocks per bh
    int id = blockIdx.x;
    int xcd = id & 7, local = id >> 3;           // local 0..127
    int bh = xcd * 4 + (local & 3);
    int qx = local >> 2;                         // 0..31
    int qblk = qx * 64 + w * 16;                 // this wave's 16 q-rows
    int b = bh >> 4, h = bh & 15;
    const short* Qb = Q  + (size_t)bh * 2048 * 64;
    const short* Kb = Kg + (size_t)bh * 2048 * 64;
    const short* Vb = Vt + (size_t)bh * 64 * 2048;
    int swz = ln & 7;

    // Q fragments (B-operand), 16 rows
    bh8 qf[2];
    #pragma unroll
    for (int c = 0; c < 2; c++)
        qf[c] = *(const bh8*)&Qb[(size_t)(qblk + ln) * 64 + c * 32 + quad * 8];

    // DMA staging map: 2 chunks K + 2 chunks V per wave; chunk c = w*2+j covers
    // tile rows [c*8, c*8+8). Linear LDS dest: lane l -> short-off c*512 + l*8
    // (row = c*8 + (l>>3), pair p = l&7). Global source pre-swizzled so
    // LDS[row][p] holds col-group p^(row&7) — matching the swizzled reads.
    const short* srcK[2]; const short* srcV[2]; int dstoff[2];
    #pragma unroll
    for (int j = 0; j < 2; j++) {
        int c = w * 2 + j;
        int row = c * 8 + (l >> 3);
        int pg = (l & 7) ^ (row & 7);
        srcK[j] = Kb + row * 64 + pg * 8;
        srcV[j] = Vb + (size_t)row * 2048 + pg * 8;
        dstoff[j] = c * 512;
    }

    // prologue: stage tile 0 into buf 0
    #pragma unroll
    for (int j = 0; j < 2; j++) {
        gload_lds16(srcK[j], SH + dstoff[j]);
        gload_lds16(srcV[j], SH + 8192 + dstoff[j]);
    }

    fx4 o[4] = {};
    float lpart = 0.f;

    for (int it = 0; it < 32; ++it) {
        int koff = (it & 1) ? 4096 : 0;
        // tile `it` DMA complete + all waves done reading buf it^1.
        asm volatile("s_waitcnt vmcnt(0) lgkmcnt(0)\n\ts_barrier" ::: "memory");
        if (it < 31) {   // issue next-tile DMA into the other buffer; waited next iter
            int noff = koff ^ 4096;
            int kg = (it + 1) * 4096, vg = (it + 1) * 64;
            #pragma unroll
            for (int j = 0; j < 2; j++) {
                gload_lds16(srcK[j] + kg, SH + noff + dstoff[j]);
                gload_lds16(srcV[j] + vg, SH + 8192 + noff + dstoff[j]);
            }
        }
        const short* ksb = SH + koff;
        const short* vsb = SH + 8192 + koff;

        // S^T[key][q] = K * Q^T  (16 q-cols)
        fx4 s[4] = {};
        #pragma unroll
        for (int mt = 0; mt < 4; mt++) {
            bh8 kf0 = *(const bh8*)&ksb[(mt * 16 + ln) * 64 + ((quad ^ swz) * 8)];
            bh8 kf1 = *(const bh8*)&ksb[(mt * 16 + ln) * 64 + (((quad + 4) ^ swz) * 8)];
            s[mt] = __builtin_amdgcn_mfma_f32_16x16x32_bf16(kf0, qf[0], s[mt], 0, 0, 0);
            s[mt] = __builtin_amdgcn_mfma_f32_16x16x32_bf16(kf1, qf[1], s[mt], 0, 0, 0);
        }

        // P = exp2(S), packed to PV B-fragments entirely in-register
        // (permlane32_swap + permlane16_swap redistribute the C-layout quads).
        float e[4][4];
        #pragma unroll
        for (int mt = 0; mt < 4; mt++) {
            #pragma unroll
            for (int r = 0; r < 4; r++)
                e[mt][r] = __builtin_amdgcn_exp2f(s[mt][r]);
            lpart += (e[mt][0] + e[mt][1]) + (e[mt][2] + e[mt][3]);
        }
        bh8 pf[2];
        #pragma unroll
        for (int c2 = 0; c2 < 2; c2++) {
            unsigned xa = pk_bf16(e[2 * c2][0], e[2 * c2][1]);
            unsigned ya = pk_bf16(e[2 * c2][2], e[2 * c2][3]);
            unsigned xb = pk_bf16(e[2 * c2 + 1][0], e[2 * c2 + 1][1]);
            unsigned yb = pk_bf16(e[2 * c2 + 1][2], e[2 * c2 + 1][3]);
            ux2 u  = __builtin_amdgcn_permlane32_swap(xa, xb, false, false);
            ux2 d02 = __builtin_amdgcn_permlane16_swap(u.x, u.y, false, false);
            ux2 u2 = __builtin_amdgcn_permlane32_swap(ya, yb, false, false);
            ux2 d13 = __builtin_amdgcn_permlane16_swap(u2.x, u2.y, false, false);
            union { unsigned u4[4]; bh8 v; } pk_;
            pk_.u4[0] = d02.x; pk_.u4[1] = d13.x;
            pk_.u4[2] = d02.y; pk_.u4[3] = d13.y;
            pf[c2] = pk_.v;
        }

        // O^T += V^T * P^T
        #pragma unroll
        for (int c2 = 0; c2 < 2; c2++) {
            #pragma unroll
            for (int dt = 0; dt < 4; dt++) {
                bh8 vf = *(const bh8*)&vsb[(dt * 16 + ln) * 64 + (((c2 * 4 + quad) ^ swz) * 8)];
                o[dt] = __builtin_amdgcn_mfma_f32_16x16x32_bf16(vf, pf[c2], o[dt], 0, 0, 0);
            }
        }
    }

    // all waves done reading K/V LDS before reusing it as epilogue scratch
    asm volatile("s_waitcnt vmcnt(0) lgkmcnt(0)\n\ts_barrier" ::: "memory");

    // epilogue: O^T -> rows via per-wave LDS transpose, scale by 1/l, bf16 out.
    float* PsF = (float*)SH + w * 1088;   // 16 rows x 68-float stride, 4352 B/wave
    int row = l >> 2, seg = l & 3;
    #pragma unroll
    for (int dt = 0; dt < 4; dt++)
        *(fx4*)&PsF[ln * 68 + dt * 16 + quad * 4] = o[dt];
    asm volatile("s_waitcnt lgkmcnt(0)" ::: "memory");
    float lr = lpart;
    lr += __shfl_xor(lr, 16);
    lr += __shfl_xor(lr, 32);
    float invr = __shfl(1.0f / lr, row);       // lane `row` holds l for q-row `row`
    int q = qblk + row;
    short* crow = Ctx + ((size_t)(b * 2048 + q)) * 1024 + h * 64 + seg * 16;
    union { short s[8]; uint4 u; } o0, o1;
    #pragma unroll
    for (int j = 0; j < 2; j++) {
        fx4 v = *(fx4*)&PsF[row * 68 + seg * 16 + j * 4];
        o0.s[j * 4 + 0] = f2bs(v[0] * invr);
        o0.s[j * 4 + 1] = f2bs(v[1] * invr);
        o0.s[j * 4 + 2] = f2bs(v[2] * invr);
        o0.s[j * 4 + 3] = f2bs(v[3] * invr);
    }
    #pragma unroll
    for (int j = 2; j < 4; j++) {
        fx4 v = *(fx4*)&PsF[row * 68 + seg * 16 + j * 4];
        o1.s[(j - 2) * 4 + 0] = f2bs(v[0] * invr);
        o1.s[(j - 2) * 4 + 1] = f2bs(v[1] * invr);
        o1.s[(j - 2) * 4 + 2] = f2bs(v[2] * invr);
        o1.s[(j - 2) * 4 + 3] = f2bs(v[3] * invr);
    }
    *(uint4*)&crow[0] = o0.u;
    *(uint4*)&crow[8] = o1.u;
}

extern "C" void kernel_launch(void* const* d_in, const int* in_sizes, int n_in,
                              void* d_out, int out_size, void* d_ws, size_t ws_size,
                              hipStream_t stream) {
    const float* emb = (const float*)d_in[0];
    const float* Wq  = (const float*)d_in[1];
    const float* bq  = (const float*)d_in[2];
    const float* Wk  = (const float*)d_in[3];
    const float* bk  = (const float*)d_in[4];
    const float* Wv  = (const float*)d_in[5];
    const float* bv  = (const float*)d_in[6];
    const float* Wo  = (const float*)d_in[7];
    const float* bo  = (const float*)d_in[8];

    char* ws = (char*)d_ws;
    const size_t MB = 1024 * 1024;
    short* Xbf  = (short*)(ws + 0);          // A panel for QKV gemm
    short* Ctx  = (short*)(ws + 0);          // flash bf16 output (overlays Xbf,
                                             // which is dead after the QKV gemm)
    short* Wt   = (short*)(ws + 8 * MB);
    short* Wot  = (short*)(ws + 17 * MB);
    short* Qb   = (short*)(ws + 19 * MB);    // pre-scaled by QSCALE
    short* Kb   = (short*)(ws + 27 * MB);
    short* Vtb  = (short*)(ws + 35 * MB);    // [B,H,Dh,S]

    cvt_emb<<<4096, 256, 0, stream>>>(emb, Xbf, MTOT * DMODEL);
    transpose_w<<<dim3(16, 16, 4), dim3(64, 4), 0, stream>>>(Wq, Wk, Wv, Wo, Wt, Wot);
    // QKV projection: 128x128 tiles, 32x24 = 768 blocks, XCD-swizzled
    gemm_bt_t<128, 128, NQKV, 0><<<768, 256, 0, stream>>>(
        Xbf, Wt, bq, bk, bv, nullptr, Qb, Kb, Vtb, nullptr);
    // attention (Q-split): 1024 blocks = 4/CU, 64 q-rows each, fused bf16 out
    flash_attn<<<1024, 256, 0, stream>>>(Qb, Kb, Vtb, Ctx);
    // output projection: 64x128 tiles, 64x8 = 512 blocks, XCD-swizzled
    gemm_bt_t<64, 128, DMODEL, 1><<<512, 256, 0, stream>>>(
        Ctx, Wot, nullptr, nullptr, nullptr, bo, nullptr, nullptr, nullptr, (float*)d_out);
}

// Round 4
// 198.883 us; speedup vs baseline: 1.0602x; 1.0125x over previous
//
#include <hip/hip_runtime.h>
#include <hip/hip_bf16.h>

// ---- problem constants ----
#define BB 2
#define SS 2048
#define DMODEL 1024
#define NHEADS 16
#define DHEAD 64
#define MTOT (BB*SS)      // 4096
#define NQKV 3072
#define QSCALE 0.18033688011112042f   // 0.125 * log2(e), folded into Q at projection

typedef short bh8 __attribute__((ext_vector_type(8)));   // 8 bf16 (4 VGPRs)
typedef float fx4 __attribute__((ext_vector_type(4)));   // MFMA accumulator
typedef unsigned int ux2 __attribute__((ext_vector_type(2)));

__device__ __forceinline__ short f2bs(float f) {
    __hip_bfloat16 h = __float2bfloat16(f);
    return *reinterpret_cast<short*>(&h);
}

__device__ __forceinline__ unsigned pk_bf16(float a, float b) {
    __hip_bfloat162 h = __float22bfloat162_rn(make_float2(a, b));
    return *reinterpret_cast<unsigned*>(&h);
}

// async global->LDS, 16B per lane. LDS dest wave-uniform base + lane*16.
__device__ __forceinline__ void gload_lds16(const short* g, short* l) {
    __builtin_amdgcn_global_load_lds(
        (const __attribute__((address_space(1))) unsigned int*)g,
        (__attribute__((address_space(3))) unsigned int*)l, 16, 0, 0);
}

// ---------------- prep: fp32 -> bf16 elementwise ----------------
__global__ __launch_bounds__(256) void cvt_emb(const float* __restrict__ x,
                                               short* __restrict__ y, int n) {
    int i = (blockIdx.x * 256 + threadIdx.x) * 4;
    if (i + 3 < n) {
        float4 v = *(const float4*)(x + i);
        short4 o;
        o.x = f2bs(v.x); o.y = f2bs(v.y); o.z = f2bs(v.z); o.w = f2bs(v.w);
        *(short4*)(y + i) = o;
    }
}

// ------------- prep: transpose + convert weights (1024x1024 each) -------------
__global__ __launch_bounds__(256) void transpose_w(
        const float* __restrict__ Wq, const float* __restrict__ Wk,
        const float* __restrict__ Wv, const float* __restrict__ Wo,
        short* __restrict__ Wt_qkv, short* __restrict__ Wot) {
    __shared__ float tile[64][65];
    int z = blockIdx.z;
    const float* src = (z == 0) ? Wq : (z == 1) ? Wk : (z == 2) ? Wv : Wo;
    short* dst = (z == 3) ? Wot : (Wt_qkv + (size_t)z * 1024 * 1024);
    int n0 = blockIdx.x * 64, k0 = blockIdx.y * 64;
    int tx = threadIdx.x, ty = threadIdx.y;
    for (int j = 0; j < 16; j++) {
        int r = ty + j * 4;
        tile[r][tx] = src[(size_t)(k0 + r) * 1024 + n0 + tx];
    }
    __syncthreads();
    for (int j = 0; j < 16; j++) {
        int r = ty + j * 4;
        dst[(size_t)(n0 + r) * 1024 + k0 + tx] = f2bs(tile[tx][r]);
    }
}

// ---------------- bt-GEMM (templated): C[m][n] = sum_k A[m][k]*Bt[n][k] ----------------
// BMxBN block, 4 waves (2x2), 3-stage global_load_lds pipeline with raw
// s_waitcnt vmcnt(CPW)+s_barrier (never vmcnt(0) mid-loop). XCD-aware 1D grid
// decode: XCD owns an M-strip so its A panel stays L2-hot; B streams once/XCD.
template<int BM, int BN, int NN, int MODE>
__global__ __launch_bounds__(256) void gemm_bt_t(
        const short* __restrict__ A, const short* __restrict__ Bt,
        const float* __restrict__ bq, const float* __restrict__ bk,
        const float* __restrict__ bv, const float* __restrict__ bo,
        short* __restrict__ Qout, short* __restrict__ Kout,
        short* __restrict__ Vtout, float* __restrict__ Cout) {
    const int K = 1024;
    constexpr int ROWS = BM + BN;        // combined A+B panel rows per k-tile
    constexpr int CPW  = ROWS / 64;      // 16-row staging chunks per wave
    constexpr int MBK  = MTOT / BM;      // m-blocks
    constexpr int STRIP = MBK / 8;       // m-tiles per XCD strip
    constexpr int MT = BM / 32, NT = BN / 32;
    __shared__ __align__(16) short S[3][ROWS * 32];

    int tid = threadIdx.x;
    int w = tid >> 6, l = tid & 63, quad = l >> 4, ln = l & 15;
    int wm = w & 1, wn = w >> 1;

    // XCD-aware decode: id%8 ~ XCD; XCD owns M-strip [xcd*STRIP, xcd*STRIP+STRIP)
    int id = blockIdx.x;
    int xcd = id & 7, local = id >> 3;
    int mi = xcd * STRIP + (local % STRIP);
    int ni = local / STRIP;
    int m0 = mi * BM, n0 = ni * BN;

    // staging chunk map: chunk c = w*CPW+j covers panel rows [c*16, c*16+16);
    // panel rows [0,BM) = A tile rows, [BM,ROWS) = B tile rows.
    const short* gsrc[CPW];
    int loff[CPW];
    #pragma unroll
    for (int j = 0; j < CPW; j++) {
        int r0 = (w * CPW + j) * 16;
        int row = r0 + (l >> 2);
        gsrc[j] = (r0 < BM ? A + (size_t)(m0 + row) * K
                           : Bt + (size_t)(n0 + row - BM) * K) + (l & 3) * 8;
        loff[j] = r0 * 32;
    }

    short *sC = &S[0][0], *sN = &S[1][0], *sN2 = &S[2][0];
    #pragma unroll
    for (int j = 0; j < CPW; j++) gload_lds16(gsrc[j], sC + loff[j]);
    #pragma unroll
    for (int j = 0; j < CPW; j++) gload_lds16(gsrc[j] + 32, sN + loff[j]);

    fx4 acc[MT][NT] = {};
    for (int it = 0; it < 32; ++it) {
        if (it < 31) {
            if constexpr (CPW == 4)
                asm volatile("s_waitcnt vmcnt(4)\n\ts_barrier" ::: "memory");
            else
                asm volatile("s_waitcnt vmcnt(3)\n\ts_barrier" ::: "memory");
        } else {
            asm volatile("s_waitcnt vmcnt(0)\n\ts_barrier" ::: "memory");
        }
        if (it < 30) {
            int k0 = (it + 2) * 32;
            #pragma unroll
            for (int j = 0; j < CPW; j++) gload_lds16(gsrc[j] + k0, sN2 + loff[j]);
        }
        bh8 af[MT], bf[NT];
        #pragma unroll
        for (int mt = 0; mt < MT; mt++)
            af[mt] = *(const bh8*)&sC[(wm * (BM / 2) + mt * 16 + ln) * 32 + quad * 8];
        #pragma unroll
        for (int nt = 0; nt < NT; nt++)
            bf[nt] = *(const bh8*)&sC[(BM + wn * (BN / 2) + nt * 16 + ln) * 32 + quad * 8];
        #pragma unroll
        for (int mt = 0; mt < MT; mt++)
            #pragma unroll
            for (int nt = 0; nt < NT; nt++)
                acc[mt][nt] = __builtin_amdgcn_mfma_f32_16x16x32_bf16(af[mt], bf[nt], acc[mt][nt], 0, 0, 0);
        short* t;
        t = sC; sC = sN; sN = sN2; sN2 = t;
    }

    #pragma unroll
    for (int mt = 0; mt < MT; mt++) {
        #pragma unroll
        for (int nt = 0; nt < NT; nt++) {
            int n = n0 + wn * (BN / 2) + nt * 16 + ln;
            int mbase = m0 + wm * (BM / 2) + mt * 16 + quad * 4;
            #pragma unroll
            for (int r = 0; r < 4; r++) {
                float v = acc[mt][nt][r];
                int m = mbase + r;
                if constexpr (MODE == 0) {
                    int which = n >> 10, nn = n & 1023, h = nn >> 6, d = nn & 63;
                    float bias = (which == 0) ? bq[nn] : (which == 1) ? bk[nn] : bv[nn];
                    v += bias;
                    int b = m >> 11, s = m & 2047;
                    if (which == 0)
                        Qout[(((size_t)(b * 16 + h) * 2048) + s) * 64 + d] = f2bs(v * QSCALE);
                    else if (which == 1)
                        Kout[(((size_t)(b * 16 + h) * 2048) + s) * 64 + d] = f2bs(v);
                    else
                        Vtout[((size_t)(b * 16 + h) * 64 + d) * 2048 + s] = f2bs(v);
                } else {
                    Cout[(size_t)m * 1024 + n] = v + bo[n];
                }
            }
        }
    }
}

// ---------------- flash attention: 2x2 wave split (q x key), fused epilogue ----------------
// v5: LDS-read-bandwidth was the bound (v4: 98k cyc/CU of ds_read_b128 vs 137k
// wall — all 4 waves read identical K/V fragments). Now wave (wq,wk) owns
// 32 q-rows x 32 keys: per-wave LDS reads halve (8 b128/iter, data-minimal)
// while occupancy stays 16 waves/CU. Key-partial O reduced across the wk pair
// once in the epilogue. Softmax row-sum offloaded to the matrix pipe:
// l = mfma(ones, P) — removes ~16 VALU adds/iter and makes numerator and
// denominator both bf16-P-consistent. s_setprio(1) wraps MFMA clusters (T5).
__global__ __launch_bounds__(256, 4) void flash_attn(
        const short* __restrict__ Q, const short* __restrict__ Kg,
        const short* __restrict__ Vt, short* __restrict__ Ctx) {
    // 32 KB: [K buf0 | K buf1 | V buf0 | V buf1], 4096 shorts each.
    // Epilogue reuse: floats [0,2176) per-wq transpose scratch,
    // [2176,6272) o-reduce (2 x 2048), [6272,6336) l-reduce.
    __shared__ __align__(16) short SH[16384];

    int tid = threadIdx.x;
    int w = tid >> 6, l = tid & 63, quad = l >> 4, ln = l & 15;
    int wq = w & 1, wk = w >> 1;
    // XCD-aware decode: 4 bh per XCD, 32 q-blocks per bh
    int id = blockIdx.x;
    int xcd = id & 7, local = id >> 3;           // local 0..127
    int bh = xcd * 4 + (local & 3);
    int qx = local >> 2;                         // 0..31
    int qblk = qx * 64 + wq * 32;                // this wave's 32 q-rows
    int b = bh >> 4, h = bh & 15;
    const short* Qb = Q  + (size_t)bh * 2048 * 64;
    const short* Kb = Kg + (size_t)bh * 2048 * 64;
    const short* Vb = Vt + (size_t)bh * 64 * 2048;
    int swz = ln & 7;

    // Q fragments (B-operand), 32 rows
    bh8 qf[2][2];
    #pragma unroll
    for (int qt = 0; qt < 2; qt++)
        #pragma unroll
        for (int c = 0; c < 2; c++)
            qf[qt][c] = *(const bh8*)&Qb[(size_t)(qblk + qt * 16 + ln) * 64 + c * 32 + quad * 8];

    // all-ones bf16 A-fragment for the l row-sum MFMA
    union { short s[8]; bh8 v; } one_;
    #pragma unroll
    for (int j = 0; j < 8; j++) one_.s[j] = 0x3F80;
    bh8 onesv = one_.v;

    // DMA staging map (block-cooperative, by raw wave id w): chunk c = w*2+j
    // covers tile rows [c*8, c*8+8). Linear LDS dest: lane l -> c*512 + l*8.
    // Global source pre-swizzled so LDS[row][p] holds col-group p^(row&7).
    const short* srcK[2]; const short* srcV[2]; int dstoff[2];
    #pragma unroll
    for (int j = 0; j < 2; j++) {
        int c = w * 2 + j;
        int row = c * 8 + (l >> 3);
        int pg = (l & 7) ^ (row & 7);
        srcK[j] = Kb + row * 64 + pg * 8;
        srcV[j] = Vb + (size_t)row * 2048 + pg * 8;
        dstoff[j] = c * 512;
    }

    // prologue: stage tile 0 into buf 0
    #pragma unroll
    for (int j = 0; j < 2; j++) {
        gload_lds16(srcK[j], SH + dstoff[j]);
        gload_lds16(srcV[j], SH + 8192 + dstoff[j]);
    }

    fx4 o[2][4] = {};
    fx4 lacc[2] = {};

    for (int it = 0; it < 32; ++it) {
        int koff = (it & 1) ? 4096 : 0;
        // tile `it` DMA complete + all waves done reading buf it^1.
        asm volatile("s_waitcnt vmcnt(0) lgkmcnt(0)\n\ts_barrier" ::: "memory");
        if (it < 31) {   // issue next-tile DMA into the other buffer; waited next iter
            int noff = koff ^ 4096;
            int kg = (it + 1) * 4096, vg = (it + 1) * 64;
            #pragma unroll
            for (int j = 0; j < 2; j++) {
                gload_lds16(srcK[j] + kg, SH + noff + dstoff[j]);
                gload_lds16(srcV[j] + vg, SH + 8192 + noff + dstoff[j]);
            }
        }
        const short* ksb = SH + koff;
        const short* vsb = SH + 8192 + koff;

        // S^T[key][q] = K * Q^T  (this wave: keys wk*32.., 32 q-cols)
        bh8 kf[2][2];
        #pragma unroll
        for (int mt = 0; mt < 2; mt++) {
            int krow = (wk * 32 + mt * 16 + ln) * 64;
            kf[mt][0] = *(const bh8*)&ksb[krow + ((quad ^ swz) * 8)];
            kf[mt][1] = *(const bh8*)&ksb[krow + (((quad + 4) ^ swz) * 8)];
        }
        fx4 s[2][2] = {};
        __builtin_amdgcn_s_setprio(1);
        #pragma unroll
        for (int mt = 0; mt < 2; mt++)
            #pragma unroll
            for (int qt = 0; qt < 2; qt++) {
                s[qt][mt] = __builtin_amdgcn_mfma_f32_16x16x32_bf16(kf[mt][0], qf[qt][0], s[qt][mt], 0, 0, 0);
                s[qt][mt] = __builtin_amdgcn_mfma_f32_16x16x32_bf16(kf[mt][1], qf[qt][1], s[qt][mt], 0, 0, 0);
            }
        __builtin_amdgcn_s_setprio(0);

        // P = exp2(S), packed to PV B-fragments entirely in-register
        // (permlane32_swap + permlane16_swap redistribute the C-layout quads).
        bh8 pf[2];
        #pragma unroll
        for (int qt = 0; qt < 2; qt++) {
            float e0[4], e1[4];
            #pragma unroll
            for (int r = 0; r < 4; r++) {
                e0[r] = __builtin_amdgcn_exp2f(s[qt][0][r]);
                e1[r] = __builtin_amdgcn_exp2f(s[qt][1][r]);
            }
            unsigned xa = pk_bf16(e0[0], e0[1]);
            unsigned ya = pk_bf16(e0[2], e0[3]);
            unsigned xb = pk_bf16(e1[0], e1[1]);
            unsigned yb = pk_bf16(e1[2], e1[3]);
            ux2 u   = __builtin_amdgcn_permlane32_swap(xa, xb, false, false);
            ux2 d02 = __builtin_amdgcn_permlane16_swap(u.x, u.y, false, false);
            ux2 u2  = __builtin_amdgcn_permlane32_swap(ya, yb, false, false);
            ux2 d13 = __builtin_amdgcn_permlane16_swap(u2.x, u2.y, false, false);
            union { unsigned u4[4]; bh8 v; } pk_;
            pk_.u4[0] = d02.x; pk_.u4[1] = d13.x;
            pk_.u4[2] = d02.y; pk_.u4[3] = d13.y;
            pf[qt] = pk_.v;
        }

        // O^T += V^T * P^T over this wave's 32 keys; l via ones-MFMA row-sum
        __builtin_amdgcn_s_setprio(1);
        #pragma unroll
        for (int dt = 0; dt < 4; dt++) {
            bh8 vf = *(const bh8*)&vsb[(dt * 16 + ln) * 64 + (((wk * 4 + quad) ^ swz) * 8)];
            o[0][dt] = __builtin_amdgcn_mfma_f32_16x16x32_bf16(vf, pf[0], o[0][dt], 0, 0, 0);
            o[1][dt] = __builtin_amdgcn_mfma_f32_16x16x32_bf16(vf, pf[1], o[1][dt], 0, 0, 0);
        }
        lacc[0] = __builtin_amdgcn_mfma_f32_16x16x32_bf16(onesv, pf[0], lacc[0], 0, 0, 0);
        lacc[1] = __builtin_amdgcn_mfma_f32_16x16x32_bf16(onesv, pf[1], lacc[1], 0, 0, 0);
        __builtin_amdgcn_s_setprio(0);
    }

    // all waves done reading K/V LDS before reusing it as epilogue scratch
    asm volatile("s_waitcnt vmcnt(0) lgkmcnt(0)\n\ts_barrier" ::: "memory");

    float* R  = (float*)SH + 2176;            // o-reduce: 2 regions x 2048 floats
    float* R2 = (float*)SH + 2176 + 4096;     // l-reduce: 2 x 32 floats

    // wk=1 waves publish their key-partial O and l
    if (wk == 1) {
        float* Rw = R + wq * 2048;
        #pragma unroll
        for (int qt = 0; qt < 2; qt++)
            #pragma unroll
            for (int dt = 0; dt < 4; dt++)
                *(fx4*)&Rw[(((qt * 4 + dt) * 4 + quad) * 16 + ln) * 4] = o[qt][dt];
        if (quad == 0) {
            R2[wq * 32 + 0 * 16 + ln] = lacc[0][0];
            R2[wq * 32 + 1 * 16 + ln] = lacc[1][0];
        }
    }
    asm volatile("s_waitcnt lgkmcnt(0)\n\ts_barrier" ::: "memory");

    if (wk == 0) {
        // reduce across the wk pair
        float* Rw = R + wq * 2048;
        float linv[2];
        #pragma unroll
        for (int qt = 0; qt < 2; qt++) {
            #pragma unroll
            for (int dt = 0; dt < 4; dt++)
                o[qt][dt] += *(const fx4*)&Rw[(((qt * 4 + dt) * 4 + quad) * 16 + ln) * 4];
            float lf = lacc[qt][0] + R2[wq * 32 + qt * 16 + ln];
            linv[qt] = 1.0f / lf;
        }
        // O^T -> rows via per-wave LDS transpose, scale by 1/l, bf16 out.
        float* PsF = (float*)SH + wq * 1088;   // 16 rows x 68-float stride
        int row = l >> 2, seg = l & 3;
        #pragma unroll
        for (int qt = 0; qt < 2; qt++) {
            #pragma unroll
            for (int dt = 0; dt < 4; dt++)
                *(fx4*)&PsF[ln * 68 + dt * 16 + quad * 4] = o[qt][dt];
            asm volatile("s_waitcnt lgkmcnt(0)" ::: "memory");
            float invr = __shfl(linv[qt], row);    // lane `row` holds l for q-row `row`
            int q = qblk + qt * 16 + row;
            short* crow = Ctx + ((size_t)(b * 2048 + q)) * 1024 + h * 64 + seg * 16;
            union { short s[8]; uint4 u; } o0, o1;
            #pragma unroll
            for (int j = 0; j < 2; j++) {
                fx4 v = *(const fx4*)&PsF[row * 68 + seg * 16 + j * 4];
                o0.s[j * 4 + 0] = f2bs(v[0] * invr);
                o0.s[j * 4 + 1] = f2bs(v[1] * invr);
                o0.s[j * 4 + 2] = f2bs(v[2] * invr);
                o0.s[j * 4 + 3] = f2bs(v[3] * invr);
            }
            #pragma unroll
            for (int j = 2; j < 4; j++) {
                fx4 v = *(const fx4*)&PsF[row * 68 + seg * 16 + j * 4];
                o1.s[(j - 2) * 4 + 0] = f2bs(v[0] * invr);
                o1.s[(j - 2) * 4 + 1] = f2bs(v[1] * invr);
                o1.s[(j - 2) * 4 + 2] = f2bs(v[2] * invr);
                o1.s[(j - 2) * 4 + 3] = f2bs(v[3] * invr);
            }
            *(uint4*)&crow[0] = o0.u;
            *(uint4*)&crow[8] = o1.u;
            asm volatile("s_waitcnt lgkmcnt(0)" ::: "memory");  // reads done before next qt overwrites
        }
    }
}

extern "C" void kernel_launch(void* const* d_in, const int* in_sizes, int n_in,
                              void* d_out, int out_size, void* d_ws, size_t ws_size,
                              hipStream_t stream) {
    const float* emb = (const float*)d_in[0];
    const float* Wq  = (const float*)d_in[1];
    const float* bq  = (const float*)d_in[2];
    const float* Wk  = (const float*)d_in[3];
    const float* bk  = (const float*)d_in[4];
    const float* Wv  = (const float*)d_in[5];
    const float* bv  = (const float*)d_in[6];
    const float* Wo  = (const float*)d_in[7];
    const float* bo  = (const float*)d_in[8];

    char* ws = (char*)d_ws;
    const size_t MB = 1024 * 1024;
    short* Xbf  = (short*)(ws + 0);          // A panel for QKV gemm
    short* Ctx  = (short*)(ws + 0);          // flash bf16 output (overlays Xbf,
                                             // which is dead after the QKV gemm)
    short* Wt   = (short*)(ws + 8 * MB);
    short* Wot  = (short*)(ws + 17 * MB);
    short* Qb   = (short*)(ws + 19 * MB);    // pre-scaled by QSCALE
    short* Kb   = (short*)(ws + 27 * MB);
    short* Vtb  = (short*)(ws + 35 * MB);    // [B,H,Dh,S]

    cvt_emb<<<4096, 256, 0, stream>>>(emb, Xbf, MTOT * DMODEL);
    transpose_w<<<dim3(16, 16, 4), dim3(64, 4), 0, stream>>>(Wq, Wk, Wv, Wo, Wt, Wot);
    // QKV projection: 128x128 tiles, 32x24 = 768 blocks, XCD-swizzled
    gemm_bt_t<128, 128, NQKV, 0><<<768, 256, 0, stream>>>(
        Xbf, Wt, bq, bk, bv, nullptr, Qb, Kb, Vtb, nullptr);
    // attention: 1024 blocks = 4/CU, 64 q-rows each, 2x2 wave split, fused bf16 out
    flash_attn<<<1024, 256, 0, stream>>>(Qb, Kb, Vtb, Ctx);
    // output projection: 64x128 tiles, 64x8 = 512 blocks, XCD-swizzled
    gemm_bt_t<64, 128, DMODEL, 1><<<512, 256, 0, stream>>>(
        Ctx, Wot, nullptr, nullptr, nullptr, bo, nullptr, nullptr, nullptr, (float*)d_out);
}

// Round 6
// 198.265 us; speedup vs baseline: 1.0635x; 1.0031x over previous
//
#include <hip/hip_runtime.h>
#include <hip/hip_bf16.h>

// ---- problem constants ----
#define BB 2
#define SS 2048
#define DMODEL 1024
#define NHEADS 16
#define DHEAD 64
#define MTOT (BB*SS)      // 4096
#define NQKV 3072
#define QSCALE 0.18033688011112042f   // 0.125 * log2(e), folded into Q at projection

typedef short bh8 __attribute__((ext_vector_type(8)));   // 8 bf16 (4 VGPRs)
typedef float fx4 __attribute__((ext_vector_type(4)));   // MFMA accumulator
typedef unsigned int ux2 __attribute__((ext_vector_type(2)));

__device__ __forceinline__ short f2bs(float f) {
    __hip_bfloat16 h = __float2bfloat16(f);
    return *reinterpret_cast<short*>(&h);
}

__device__ __forceinline__ unsigned pk_bf16(float a, float b) {
    __hip_bfloat162 h = __float22bfloat162_rn(make_float2(a, b));
    return *reinterpret_cast<unsigned*>(&h);
}

// async global->LDS, 16B per lane. LDS dest wave-uniform base + lane*16.
__device__ __forceinline__ void gload_lds16(const short* g, short* l) {
    __builtin_amdgcn_global_load_lds(
        (const __attribute__((address_space(1))) unsigned int*)g,
        (__attribute__((address_space(3))) unsigned int*)l, 16, 0, 0);
}

// ---------------- prep: cvt emb (blocks 0..4095) + transpose weights (4096..5119) ----------------
__global__ __launch_bounds__(256) void prep(
        const float* __restrict__ emb, short* __restrict__ Xbf,
        const float* __restrict__ Wq, const float* __restrict__ Wk,
        const float* __restrict__ Wv, const float* __restrict__ Wo,
        short* __restrict__ Wt_qkv, short* __restrict__ Wot) {
    __shared__ float tile[64][65];
    int bid = blockIdx.x, tid = threadIdx.x;
    if (bid < 4096) {
        int i = (bid * 256 + tid) * 4;          // exactly covers MTOT*DMODEL
        float4 v = *(const float4*)(emb + i);
        short4 o;
        o.x = f2bs(v.x); o.y = f2bs(v.y); o.z = f2bs(v.z); o.w = f2bs(v.w);
        *(short4*)(Xbf + i) = o;
    } else {
        int b2 = bid - 4096;
        int bx = b2 & 15, by = (b2 >> 4) & 15, z = b2 >> 8;
        const float* src = (z == 0) ? Wq : (z == 1) ? Wk : (z == 2) ? Wv : Wo;
        short* dst = (z == 3) ? Wot : (Wt_qkv + (size_t)z * 1024 * 1024);
        int n0 = bx * 64, k0 = by * 64;
        int tx = tid & 63, ty = tid >> 6;
        for (int j = 0; j < 16; j++) {
            int r = ty + j * 4;
            tile[r][tx] = src[(size_t)(k0 + r) * 1024 + n0 + tx];
        }
        __syncthreads();
        for (int j = 0; j < 16; j++) {
            int r = ty + j * 4;
            dst[(size_t)(n0 + r) * 1024 + k0 + tx] = f2bs(tile[tx][r]);
        }
    }
}

// ---------------- bt-GEMM (templated): C[m][n] = sum_k A[m][k]*Bt[n][k] ----------------
// BMxBN block, 4 waves (2x2), 3-stage global_load_lds pipeline with raw
// s_waitcnt vmcnt(CPW)+s_barrier (never vmcnt(0) mid-loop). XCD-aware 1D grid.
// v7 (MODE 0): `which` is BLOCK-uniform (n0>>10; 128-wide tiles never cross the
// 1024 boundaries). Q/K blocks swap MFMA operand order (legal: 16x16x32 A/B
// fragments share one lane layout) so the C fragment has row=d, col=s — then
// flash's verified LDS-transpose pattern applies verbatim (reg axis and inner
// tile axis are BOTH d) and stores are coalesced 16B [s][d] rows, with bias
// applied post-transpose via 4 vector loads. V blocks keep non-swapped acc +
// the verified permlane pack -> 16B V^T stores. (Round-5 bug: transpose with
// non-swapped acc mixed the m and d axes in the scratch column index.)
template<int BM, int BN, int NN, int MODE>
__global__ __launch_bounds__(256) void gemm_bt_t(
        const short* __restrict__ A, const short* __restrict__ Bt,
        const float* __restrict__ bq, const float* __restrict__ bk,
        const float* __restrict__ bv, const float* __restrict__ bo,
        short* __restrict__ Qout, short* __restrict__ Kout,
        short* __restrict__ Vtout, float* __restrict__ Cout) {
    const int K = 1024;
    constexpr int ROWS = BM + BN;        // combined A+B panel rows per k-tile
    constexpr int CPW  = ROWS / 64;      // 16-row staging chunks per wave
    constexpr int MBK  = MTOT / BM;      // m-blocks
    constexpr int STRIP = MBK / 8;       // m-tiles per XCD strip
    constexpr int MT = BM / 32, NT = BN / 32;
    __shared__ __align__(16) short S[3][ROWS * 32];

    int tid = threadIdx.x;
    int w = tid >> 6, l = tid & 63, quad = l >> 4, ln = l & 15;
    int wm = w & 1, wn = w >> 1;

    // XCD-aware decode: id%8 ~ XCD; XCD owns M-strip [xcd*STRIP, xcd*STRIP+STRIP)
    int id = blockIdx.x;
    int xcd = id & 7, local = id >> 3;
    int mi = xcd * STRIP + (local % STRIP);
    int ni = local / STRIP;
    int m0 = mi * BM, n0 = ni * BN;

    // block-uniform output kind (MODE 0): 0=Q 1=K 2=V
    const int which = (MODE == 0) ? (n0 >> 10) : 2;
    const bool swp = (MODE == 0) && (which != 2);

    // staging chunk map: chunk c = w*CPW+j covers panel rows [c*16, c*16+16);
    // panel rows [0,BM) = A tile rows, [BM,ROWS) = B tile rows.
    const short* gsrc[CPW];
    int loff[CPW];
    #pragma unroll
    for (int j = 0; j < CPW; j++) {
        int r0 = (w * CPW + j) * 16;
        int row = r0 + (l >> 2);
        gsrc[j] = (r0 < BM ? A + (size_t)(m0 + row) * K
                           : Bt + (size_t)(n0 + row - BM) * K) + (l & 3) * 8;
        loff[j] = r0 * 32;
    }

    short *sC = &S[0][0], *sN = &S[1][0], *sN2 = &S[2][0];
    #pragma unroll
    for (int j = 0; j < CPW; j++) gload_lds16(gsrc[j], sC + loff[j]);
    #pragma unroll
    for (int j = 0; j < CPW; j++) gload_lds16(gsrc[j] + 32, sN + loff[j]);

    fx4 acc[MT][NT] = {};
    for (int it = 0; it < 32; ++it) {
        if (it < 31) {
            if constexpr (CPW == 4)
                asm volatile("s_waitcnt vmcnt(4)\n\ts_barrier" ::: "memory");
            else
                asm volatile("s_waitcnt vmcnt(3)\n\ts_barrier" ::: "memory");
        } else {
            asm volatile("s_waitcnt vmcnt(0)\n\ts_barrier" ::: "memory");
        }
        if (it < 30) {
            int k0 = (it + 2) * 32;
            #pragma unroll
            for (int j = 0; j < CPW; j++) gload_lds16(gsrc[j] + k0, sN2 + loff[j]);
        }
        bh8 af[MT], bf[NT];
        #pragma unroll
        for (int mt = 0; mt < MT; mt++)
            af[mt] = *(const bh8*)&sC[(wm * (BM / 2) + mt * 16 + ln) * 32 + quad * 8];
        #pragma unroll
        for (int nt = 0; nt < NT; nt++)
            bf[nt] = *(const bh8*)&sC[(BM + wn * (BN / 2) + nt * 16 + ln) * 32 + quad * 8];
        if (!swp) {
            #pragma unroll
            for (int mt = 0; mt < MT; mt++)
                #pragma unroll
                for (int nt = 0; nt < NT; nt++)
                    acc[mt][nt] = __builtin_amdgcn_mfma_f32_16x16x32_bf16(af[mt], bf[nt], acc[mt][nt], 0, 0, 0);
        } else {
            // swapped: C row axis = n (d), col axis = m (s)
            #pragma unroll
            for (int mt = 0; mt < MT; mt++)
                #pragma unroll
                for (int nt = 0; nt < NT; nt++)
                    acc[mt][nt] = __builtin_amdgcn_mfma_f32_16x16x32_bf16(bf[nt], af[mt], acc[mt][nt], 0, 0, 0);
        }
        short* t;
        t = sC; sC = sN; sN = sN2; sN2 = t;
    }

    if constexpr (MODE == 0) {
        int nbase = n0 + wn * 64;
        int nn0 = nbase & 1023;          // multiple of 64 (this wave's 64-d base)
        int h = nn0 >> 6;
        int mbase_w = m0 + wm * 64;      // 64-aligned, never crosses batch
        int bb_ = mbase_w >> 11, s0 = mbase_w & 2047;

        if (which == 2) {
            // V (non-swapped acc: row=m, col=d=nt*16+ln). Bias per-lane, then
            // permlane pack -> lane holds 8 consecutive s at fixed d; 16B stores.
            #pragma unroll
            for (int nt = 0; nt < NT; nt++) {
                float bias = bv[nn0 + nt * 16 + ln];
                #pragma unroll
                for (int mt = 0; mt < MT; mt++)
                    #pragma unroll
                    for (int r = 0; r < 4; r++)
                        acc[mt][nt][r] += bias;
            }
            #pragma unroll
            for (int nt = 0; nt < NT; nt++) {
                int d = nt * 16 + ln;
                short* vrow = Vtout + ((size_t)(bb_ * 16 + h) * 64 + d) * 2048 + s0;
                #pragma unroll
                for (int mp = 0; mp < MT / 2; mp++) {
                    fx4 ea = acc[2 * mp][nt], eb = acc[2 * mp + 1][nt];
                    unsigned xa = pk_bf16(ea[0], ea[1]);
                    unsigned ya = pk_bf16(ea[2], ea[3]);
                    unsigned xb = pk_bf16(eb[0], eb[1]);
                    unsigned yb = pk_bf16(eb[2], eb[3]);
                    ux2 u   = __builtin_amdgcn_permlane32_swap(xa, xb, false, false);
                    ux2 d02 = __builtin_amdgcn_permlane16_swap(u.x, u.y, false, false);
                    ux2 u2  = __builtin_amdgcn_permlane32_swap(ya, yb, false, false);
                    ux2 d13 = __builtin_amdgcn_permlane16_swap(u2.x, u2.y, false, false);
                    union { unsigned u4[4]; uint4 v; } pk_;
                    pk_.u4[0] = d02.x; pk_.u4[1] = d13.x;
                    pk_.u4[2] = d02.y; pk_.u4[3] = d13.y;
                    *(uint4*)(vrow + (mp * 32 + quad * 8)) = pk_.v;
                }
            }
        } else {
            // Q/K (swapped acc: value at d = nt*16+quad*4+r, s = mt*16+ln).
            // Flash-pattern per-wave LDS transpose (reg axis + nt axis both d),
            // bias applied post-transpose (d lane-contiguous -> 4 fx4 loads).
            const float* bptr = (which == 0) ? bq : bk;
            float scl = (which == 0) ? QSCALE : 1.0f;
            short* out = (which == 0) ? Qout : Kout;
            // all waves' staging reads retired before S is reused as scratch
            asm volatile("s_waitcnt lgkmcnt(0)\n\ts_barrier" ::: "memory");
            float* PsF = (float*)&S[0][0] + w * 1088;   // 16 rows x 68-float stride
            int row = l >> 2, seg = l & 3;
            fx4 bjv[4];
            #pragma unroll
            for (int j = 0; j < 4; j++)
                bjv[j] = *(const fx4*)&bptr[nn0 + seg * 16 + j * 4];
            #pragma unroll
            for (int mt = 0; mt < MT; mt++) {
                #pragma unroll
                for (int nt = 0; nt < NT; nt++)
                    *(fx4*)&PsF[ln * 68 + nt * 16 + quad * 4] = acc[mt][nt];
                asm volatile("s_waitcnt lgkmcnt(0)" ::: "memory");
                int s_ = s0 + mt * 16 + row;
                short* crow = out + (((size_t)(bb_ * 16 + h) * 2048) + s_) * 64 + seg * 16;
                union { short sv[8]; uint4 u; } o0, o1;
                #pragma unroll
                for (int j = 0; j < 2; j++) {
                    fx4 v = *(const fx4*)&PsF[row * 68 + seg * 16 + j * 4];
                    o0.sv[j * 4 + 0] = f2bs((v[0] + bjv[j][0]) * scl);
                    o0.sv[j * 4 + 1] = f2bs((v[1] + bjv[j][1]) * scl);
                    o0.sv[j * 4 + 2] = f2bs((v[2] + bjv[j][2]) * scl);
                    o0.sv[j * 4 + 3] = f2bs((v[3] + bjv[j][3]) * scl);
                }
                #pragma unroll
                for (int j = 2; j < 4; j++) {
                    fx4 v = *(const fx4*)&PsF[row * 68 + seg * 16 + j * 4];
                    o1.sv[(j - 2) * 4 + 0] = f2bs((v[0] + bjv[j][0]) * scl);
                    o1.sv[(j - 2) * 4 + 1] = f2bs((v[1] + bjv[j][1]) * scl);
                    o1.sv[(j - 2) * 4 + 2] = f2bs((v[2] + bjv[j][2]) * scl);
                    o1.sv[(j - 2) * 4 + 3] = f2bs((v[3] + bjv[j][3]) * scl);
                }
                *(uint4*)&crow[0] = o0.u;
                *(uint4*)&crow[8] = o1.u;
                asm volatile("s_waitcnt lgkmcnt(0)" ::: "memory");  // reads done before next mt overwrites
            }
        }
    } else {
        #pragma unroll
        for (int mt = 0; mt < MT; mt++) {
            #pragma unroll
            for (int nt = 0; nt < NT; nt++) {
                int n = n0 + wn * (BN / 2) + nt * 16 + ln;
                int mbase = m0 + wm * (BM / 2) + mt * 16 + quad * 4;
                #pragma unroll
                for (int r = 0; r < 4; r++) {
                    int m = mbase + r;
                    Cout[(size_t)m * 1024 + n] = acc[mt][nt][r] + bo[n];
                }
            }
        }
    }
}

// ---------------- flash attention: 2x2 wave split (q x key), fused epilogue ----------------
// v5 (unchanged): wave (wq,wk) owns 32 q-rows x 32 keys; per-wave LDS reads
// data-minimal; key-partial O reduced across the wk pair in the epilogue;
// l = mfma(ones, P) on the matrix pipe; s_setprio(1) around MFMA clusters.
__global__ __launch_bounds__(256, 4) void flash_attn(
        const short* __restrict__ Q, const short* __restrict__ Kg,
        const short* __restrict__ Vt, short* __restrict__ Ctx) {
    // 32 KB: [K buf0 | K buf1 | V buf0 | V buf1], 4096 shorts each.
    // Epilogue reuse: floats [0,2176) per-wq transpose scratch,
    // [2176,6272) o-reduce (2 x 2048), [6272,6336) l-reduce.
    __shared__ __align__(16) short SH[16384];

    int tid = threadIdx.x;
    int w = tid >> 6, l = tid & 63, quad = l >> 4, ln = l & 15;
    int wq = w & 1, wk = w >> 1;
    // XCD-aware decode: 4 bh per XCD, 32 q-blocks per bh
    int id = blockIdx.x;
    int xcd = id & 7, local = id >> 3;           // local 0..127
    int bh = xcd * 4 + (local & 3);
    int qx = local >> 2;                         // 0..31
    int qblk = qx * 64 + wq * 32;                // this wave's 32 q-rows
    int b = bh >> 4, h = bh & 15;
    const short* Qb = Q  + (size_t)bh * 2048 * 64;
    const short* Kb = Kg + (size_t)bh * 2048 * 64;
    const short* Vb = Vt + (size_t)bh * 64 * 2048;
    int swz = ln & 7;

    // Q fragments (B-operand), 32 rows
    bh8 qf[2][2];
    #pragma unroll
    for (int qt = 0; qt < 2; qt++)
        #pragma unroll
        for (int c = 0; c < 2; c++)
            qf[qt][c] = *(const bh8*)&Qb[(size_t)(qblk + qt * 16 + ln) * 64 + c * 32 + quad * 8];

    // all-ones bf16 A-fragment for the l row-sum MFMA
    union { short s[8]; bh8 v; } one_;
    #pragma unroll
    for (int j = 0; j < 8; j++) one_.s[j] = 0x3F80;
    bh8 onesv = one_.v;

    // DMA staging map (block-cooperative, by raw wave id w): chunk c = w*2+j
    // covers tile rows [c*8, c*8+8). Linear LDS dest: lane l -> c*512 + l*8.
    // Global source pre-swizzled so LDS[row][p] holds col-group p^(row&7).
    const short* srcK[2]; const short* srcV[2]; int dstoff[2];
    #pragma unroll
    for (int j = 0; j < 2; j++) {
        int c = w * 2 + j;
        int row = c * 8 + (l >> 3);
        int pg = (l & 7) ^ (row & 7);
        srcK[j] = Kb + row * 64 + pg * 8;
        srcV[j] = Vb + (size_t)row * 2048 + pg * 8;
        dstoff[j] = c * 512;
    }

    // prologue: stage tile 0 into buf 0
    #pragma unroll
    for (int j = 0; j < 2; j++) {
        gload_lds16(srcK[j], SH + dstoff[j]);
        gload_lds16(srcV[j], SH + 8192 + dstoff[j]);
    }

    fx4 o[2][4] = {};
    fx4 lacc[2] = {};

    for (int it = 0; it < 32; ++it) {
        int koff = (it & 1) ? 4096 : 0;
        // tile `it` DMA complete + all waves done reading buf it^1.
        asm volatile("s_waitcnt vmcnt(0) lgkmcnt(0)\n\ts_barrier" ::: "memory");
        if (it < 31) {   // issue next-tile DMA into the other buffer; waited next iter
            int noff = koff ^ 4096;
            int kg = (it + 1) * 4096, vg = (it + 1) * 64;
            #pragma unroll
            for (int j = 0; j < 2; j++) {
                gload_lds16(srcK[j] + kg, SH + noff + dstoff[j]);
                gload_lds16(srcV[j] + vg, SH + 8192 + noff + dstoff[j]);
            }
        }
        const short* ksb = SH + koff;
        const short* vsb = SH + 8192 + koff;

        // S^T[key][q] = K * Q^T  (this wave: keys wk*32.., 32 q-cols)
        bh8 kf[2][2];
        #pragma unroll
        for (int mt = 0; mt < 2; mt++) {
            int krow = (wk * 32 + mt * 16 + ln) * 64;
            kf[mt][0] = *(const bh8*)&ksb[krow + ((quad ^ swz) * 8)];
            kf[mt][1] = *(const bh8*)&ksb[krow + (((quad + 4) ^ swz) * 8)];
        }
        fx4 s[2][2] = {};
        __builtin_amdgcn_s_setprio(1);
        #pragma unroll
        for (int mt = 0; mt < 2; mt++)
            #pragma unroll
            for (int qt = 0; qt < 2; qt++) {
                s[qt][mt] = __builtin_amdgcn_mfma_f32_16x16x32_bf16(kf[mt][0], qf[qt][0], s[qt][mt], 0, 0, 0);
                s[qt][mt] = __builtin_amdgcn_mfma_f32_16x16x32_bf16(kf[mt][1], qf[qt][1], s[qt][mt], 0, 0, 0);
            }
        __builtin_amdgcn_s_setprio(0);

        // P = exp2(S), packed to PV B-fragments entirely in-register
        // (permlane32_swap + permlane16_swap redistribute the C-layout quads).
        bh8 pf[2];
        #pragma unroll
        for (int qt = 0; qt < 2; qt++) {
            float e0[4], e1[4];
            #pragma unroll
            for (int r = 0; r < 4; r++) {
                e0[r] = __builtin_amdgcn_exp2f(s[qt][0][r]);
                e1[r] = __builtin_amdgcn_exp2f(s[qt][1][r]);
            }
            unsigned xa = pk_bf16(e0[0], e0[1]);
            unsigned ya = pk_bf16(e0[2], e0[3]);
            unsigned xb = pk_bf16(e1[0], e1[1]);
            unsigned yb = pk_bf16(e1[2], e1[3]);
            ux2 u   = __builtin_amdgcn_permlane32_swap(xa, xb, false, false);
            ux2 d02 = __builtin_amdgcn_permlane16_swap(u.x, u.y, false, false);
            ux2 u2  = __builtin_amdgcn_permlane32_swap(ya, yb, false, false);
            ux2 d13 = __builtin_amdgcn_permlane16_swap(u2.x, u2.y, false, false);
            union { unsigned u4[4]; bh8 v; } pk_;
            pk_.u4[0] = d02.x; pk_.u4[1] = d13.x;
            pk_.u4[2] = d02.y; pk_.u4[3] = d13.y;
            pf[qt] = pk_.v;
        }

        // O^T += V^T * P^T over this wave's 32 keys; l via ones-MFMA row-sum
        __builtin_amdgcn_s_setprio(1);
        #pragma unroll
        for (int dt = 0; dt < 4; dt++) {
            bh8 vf = *(const bh8*)&vsb[(dt * 16 + ln) * 64 + (((wk * 4 + quad) ^ swz) * 8)];
            o[0][dt] = __builtin_amdgcn_mfma_f32_16x16x32_bf16(vf, pf[0], o[0][dt], 0, 0, 0);
            o[1][dt] = __builtin_amdgcn_mfma_f32_16x16x32_bf16(vf, pf[1], o[1][dt], 0, 0, 0);
        }
        lacc[0] = __builtin_amdgcn_mfma_f32_16x16x32_bf16(onesv, pf[0], lacc[0], 0, 0, 0);
        lacc[1] = __builtin_amdgcn_mfma_f32_16x16x32_bf16(onesv, pf[1], lacc[1], 0, 0, 0);
        __builtin_amdgcn_s_setprio(0);
    }

    // all waves done reading K/V LDS before reusing it as epilogue scratch
    asm volatile("s_waitcnt vmcnt(0) lgkmcnt(0)\n\ts_barrier" ::: "memory");

    float* R  = (float*)SH + 2176;            // o-reduce: 2 regions x 2048 floats
    float* R2 = (float*)SH + 2176 + 4096;     // l-reduce: 2 x 32 floats

    // wk=1 waves publish their key-partial O and l
    if (wk == 1) {
        float* Rw = R + wq * 2048;
        #pragma unroll
        for (int qt = 0; qt < 2; qt++)
            #pragma unroll
            for (int dt = 0; dt < 4; dt++)
                *(fx4*)&Rw[(((qt * 4 + dt) * 4 + quad) * 16 + ln) * 4] = o[qt][dt];
        if (quad == 0) {
            R2[wq * 32 + 0 * 16 + ln] = lacc[0][0];
            R2[wq * 32 + 1 * 16 + ln] = lacc[1][0];
        }
    }
    asm volatile("s_waitcnt lgkmcnt(0)\n\ts_barrier" ::: "memory");

    if (wk == 0) {
        // reduce across the wk pair
        float* Rw = R + wq * 2048;
        float linv[2];
        #pragma unroll
        for (int qt = 0; qt < 2; qt++) {
            #pragma unroll
            for (int dt = 0; dt < 4; dt++)
                o[qt][dt] += *(const fx4*)&Rw[(((qt * 4 + dt) * 4 + quad) * 16 + ln) * 4];
            float lf = lacc[qt][0] + R2[wq * 32 + qt * 16 + ln];
            linv[qt] = 1.0f / lf;
        }
        // O^T -> rows via per-wave LDS transpose, scale by 1/l, bf16 out.
        float* PsF = (float*)SH + wq * 1088;   // 16 rows x 68-float stride
        int row = l >> 2, seg = l & 3;
        #pragma unroll
        for (int qt = 0; qt < 2; qt++) {
            #pragma unroll
            for (int dt = 0; dt < 4; dt++)
                *(fx4*)&PsF[ln * 68 + dt * 16 + quad * 4] = o[qt][dt];
            asm volatile("s_waitcnt lgkmcnt(0)" ::: "memory");
            float invr = __shfl(linv[qt], row);    // lane `row` holds l for q-row `row`
            int q = qblk + qt * 16 + row;
            short* crow = Ctx + ((size_t)(b * 2048 + q)) * 1024 + h * 64 + seg * 16;
            union { short s[8]; uint4 u; } o0, o1;
            #pragma unroll
            for (int j = 0; j < 2; j++) {
                fx4 v = *(const fx4*)&PsF[row * 68 + seg * 16 + j * 4];
                o0.s[j * 4 + 0] = f2bs(v[0] * invr);
                o0.s[j * 4 + 1] = f2bs(v[1] * invr);
                o0.s[j * 4 + 2] = f2bs(v[2] * invr);
                o0.s[j * 4 + 3] = f2bs(v[3] * invr);
            }
            #pragma unroll
            for (int j = 2; j < 4; j++) {
                fx4 v = *(const fx4*)&PsF[row * 68 + seg * 16 + j * 4];
                o1.s[(j - 2) * 4 + 0] = f2bs(v[0] * invr);
                o1.s[(j - 2) * 4 + 1] = f2bs(v[1] * invr);
                o1.s[(j - 2) * 4 + 2] = f2bs(v[2] * invr);
                o1.s[(j - 2) * 4 + 3] = f2bs(v[3] * invr);
            }
            *(uint4*)&crow[0] = o0.u;
            *(uint4*)&crow[8] = o1.u;
            asm volatile("s_waitcnt lgkmcnt(0)" ::: "memory");  // reads done before next qt overwrites
        }
    }
}

extern "C" void kernel_launch(void* const* d_in, const int* in_sizes, int n_in,
                              void* d_out, int out_size, void* d_ws, size_t ws_size,
                              hipStream_t stream) {
    const float* emb = (const float*)d_in[0];
    const float* Wq  = (const float*)d_in[1];
    const float* bq  = (const float*)d_in[2];
    const float* Wk  = (const float*)d_in[3];
    const float* bk  = (const float*)d_in[4];
    const float* Wv  = (const float*)d_in[5];
    const float* bv  = (const float*)d_in[6];
    const float* Wo  = (const float*)d_in[7];
    const float* bo  = (const float*)d_in[8];

    char* ws = (char*)d_ws;
    const size_t MB = 1024 * 1024;
    short* Xbf  = (short*)(ws + 0);          // A panel for QKV gemm
    short* Ctx  = (short*)(ws + 0);          // flash bf16 output (overlays Xbf,
                                             // which is dead after the QKV gemm)
    short* Wt   = (short*)(ws + 8 * MB);
    short* Wot  = (short*)(ws + 17 * MB);
    short* Qb   = (short*)(ws + 19 * MB);    // pre-scaled by QSCALE
    short* Kb   = (short*)(ws + 27 * MB);
    short* Vtb  = (short*)(ws + 35 * MB);    // [B,H,Dh,S]

    // fused prep: emb->bf16 (4096 blocks) + 4x weight transpose (1024 blocks)
    prep<<<5120, 256, 0, stream>>>(emb, Xbf, Wq, Wk, Wv, Wo, Wt, Wot);
    // QKV projection: 128x128 tiles, 32x24 = 768 blocks, XCD-swizzled
    gemm_bt_t<128, 128, NQKV, 0><<<768, 256, 0, stream>>>(
        Xbf, Wt, bq, bk, bv, nullptr, Qb, Kb, Vtb, nullptr);
    // attention: 1024 blocks = 4/CU, 64 q-rows each, 2x2 wave split, fused bf16 out
    flash_attn<<<1024, 256, 0, stream>>>(Qb, Kb, Vtb, Ctx);
    // output projection: 64x128 tiles, 64x8 = 512 blocks, XCD-swizzled
    gemm_bt_t<64, 128, DMODEL, 1><<<512, 256, 0, stream>>>(
        Ctx, Wot, nullptr, nullptr, nullptr, bo, nullptr, nullptr, nullptr, (float*)d_out);
}